// Round 2
// baseline (2572.645 us; speedup 1.0000x reference)
//
#include <hip/hip_runtime.h>

typedef __attribute__((ext_vector_type(8))) short short8;
typedef __attribute__((ext_vector_type(4))) float float4v;
typedef __attribute__((ext_vector_type(4))) unsigned short ushort4v;

#define NBOX 13392   // 108*124 bev cells
#define DC 108
#define WC 124
#define ZC 9
#define KOFT 2304    // 9*256
#define NPAD_OFT 13440
#define NPIX 3348    // 62*54
#define NPAD_CONV 3392
#define KCONV1 11520 // 1280*9

__device__ __forceinline__ unsigned short f2bf(float f) {
  union { float f; unsigned int i; } v; v.f = f;
  unsigned int r = v.i + 0x7FFFu + ((v.i >> 16) & 1u);
  return (unsigned short)(r >> 16);
}
__device__ __forceinline__ float bf2f(unsigned short u) {
  union { unsigned int i; float f; } v; v.i = ((unsigned int)u) << 16; return v.f;
}

// ---------------- alpha/beta epilogue constants (7 groups of 256) ----------
__global__ void k_alpha_beta(const float* __restrict__ oft_b,
                             const float* __restrict__ g1, const float* __restrict__ b1,
                             const float* __restrict__ m1, const float* __restrict__ v1,
                             const float* __restrict__ g2, const float* __restrict__ b2,
                             const float* __restrict__ m2, const float* __restrict__ v2,
                             float* __restrict__ ALPHA, float* __restrict__ BETA) {
  int g = blockIdx.x, c = threadIdx.x;
  float al, be;
  if (g < 5) { al = 1.f; be = oft_b[g * 256 + c]; }
  else {
    const float* gg = (g == 5) ? g1 : g2;
    const float* bb = (g == 5) ? b1 : b2;
    const float* mm = (g == 5) ? m1 : m2;
    const float* vv = (g == 5) ? v1 : v2;
    al = gg[c] / sqrtf(vv[c] + 1e-5f);
    be = bb[c] - mm[c] * al;
  }
  ALPHA[g * 256 + c] = al; BETA[g * 256 + c] = be;
}

// ---------------- permute oft weights: k = c*9+z  ->  k' = z*256+c, f32->bf16
__global__ void k_wperm(const float* __restrict__ w, unsigned short* __restrict__ wp) {
  int idx = blockIdx.x * 256 + threadIdx.x;  // < 5*256*2304
  int kp = idx % KOFT;
  int soc = idx / KOFT;
  int z = kp >> 8, c = kp & 255;
  wp[idx] = f2bf(w[(size_t)soc * KOFT + c * 9 + z]);
}

// ---------------- plain f32 -> bf16 convert (conv weights) -----------------
__global__ void k_cvt(const float* __restrict__ in, unsigned short* __restrict__ out) {
  int idx = blockIdx.x * 256 + threadIdx.x;   // grid sized exactly
  out[idx] = f2bf(in[idx]);
}

// ---------------- bbox projection (scale-independent) ----------------------
__global__ void k_bbox(const float* __restrict__ calib, float* __restrict__ bbox) {
  int idx = blockIdx.x * 256 + threadIdx.x;
  if (idx >= ZC * NBOX) return;
  int z = idx / NBOX, n = idx % NBOX;
  int d = n / WC, wj = n % WC;
  float P[12];
#pragma unroll
  for (int i = 0; i < 12; ++i) P[i] = calib[i];
  auto proj = [&](int k, int i, int j, float& nx, float& ny) {
    float X = 0.64f * (float)i;
    float Y = 39.68f - 0.64f * (float)j;
    float Z = 2.76f - 0.64f * (float)k;
    float hx = P[0] * X + P[1] * Y + P[2]  * Z + P[3];
    float hy = P[4] * X + P[5] * Y + P[6]  * Z + P[7];
    float hz = P[8] * X + P[9] * Y + P[10] * Z + P[11];
    float px = hx / hz, py = hy / hz;
    nx = 2.f * px / 1280.f - 1.f; nx = fminf(fmaxf(nx, -1.f), 1.f);
    ny = 2.f * py / 384.f  - 1.f; ny = fminf(fmaxf(ny, -1.f), 1.f);
  };
  float ax, ay, bx, by, cx, cy, dx, dy;
  proj(z,     d,     wj,     ax, ay);   // (k, i,   j)
  proj(z,     d + 1, wj,     bx, by);   // (k, i+1, j)
  proj(z + 1, d + 1, wj + 1, cx, cy);   // (k+1, i+1, j+1)
  proj(z + 1, d,     wj + 1, dx, dy);   // (k+1, i,   j+1)
  float4v o;
  o[0] = fminf(ax, bx); o[1] = fminf(ay, by);
  o[2] = fmaxf(cx, dx); o[3] = fmaxf(cy, dy);
  *(float4v*)(bbox + (size_t)idx * 4) = o;
}

// ---------------- zero the vox pad rows ------------------------------------
__global__ void k_zeropad(unsigned short* __restrict__ A) {
  int idx = blockIdx.x * 256 + threadIdx.x;   // grid sized exactly 48*2304
  A[(size_t)NBOX * KOFT + idx] = 0;
}

// ---------------- integral image: row cumsum (f32 [C][H][W] -> f32 [H][W][C])
__global__ void k_rowsum(const float* __restrict__ f, float* __restrict__ ii,
                         int Hf, int Wf) {
  int c = threadIdx.x, h = blockIdx.x;
  const float* src = f + ((size_t)c * Hf + h) * Wf;
  float* dst = ii + (size_t)h * Wf * 256 + c;
  float acc = 0.f;
  for (int w = 0; w < Wf; ++w) { acc += src[w]; dst[(size_t)w * 256] = acc; }
}

// ---------------- integral image: column cumsum in place -------------------
__global__ void k_colsum(float* __restrict__ ii, int Hf, int Wf) {
  int c = threadIdx.x, w = blockIdx.x;
  float* p = ii + (size_t)w * 256 + c;
  size_t stride = (size_t)Wf * 256;
  float acc = 0.f;
  for (int h = 0; h < Hf; ++h) { acc += p[h * stride]; p[h * stride] = acc; }
}

// ---------------- box sampler: vox[n][z*256+c] (bf16) ----------------------
__global__ void k_sample(const float* __restrict__ ii, const float* __restrict__ bbox,
                         unsigned short* __restrict__ vox, int Hf, int Wf, float areaScale) {
  int n = blockIdx.x, c = threadIdx.x;
  for (int z = 0; z < ZC; ++z) {
    const float* bb = bbox + ((size_t)z * NBOX + n) * 4;
    float x0 = bb[0], y0 = bb[1], x1 = bb[2], y1 = bb[3];
    float rawA = (x1 - x0) * (y1 - y0) * areaScale;
    float area = rawA + 1e-6f;
    float inv = (area > 1e-6f) ? (1.f / area) : 0.f;
    float acc = 0.f;
#pragma unroll
    for (int pt = 0; pt < 4; ++pt) {
      float gx = (pt == 0 || pt == 3) ? x0 : x1;
      float gy = (pt == 0 || pt == 2) ? y0 : y1;
      float sign = (pt < 2) ? 1.f : -1.f;
      float u = (gx + 1.f) * ((float)Wf * 0.5f) - 0.5f;
      float v = (gy + 1.f) * ((float)Hf * 0.5f) - 0.5f;
      float uf = floorf(u), vf = floorf(v);
      float wx = u - uf, wy = v - vf;
      int xi = (int)uf, yi = (int)vf;
      bool okx0 = (xi >= 0) && (xi < Wf);
      bool okx1 = (xi + 1 >= 0) && (xi + 1 < Wf);
      bool oky0 = (yi >= 0) && (yi < Hf);
      bool oky1 = (yi + 1 >= 0) && (yi + 1 < Hf);
      float s = 0.f;
      if (okx0 && oky0) s += ii[((size_t)yi * Wf + xi) * 256 + c]           * (1.f - wx) * (1.f - wy);
      if (okx1 && oky0) s += ii[((size_t)yi * Wf + xi + 1) * 256 + c]       * wx * (1.f - wy);
      if (okx0 && oky1) s += ii[((size_t)(yi + 1) * Wf + xi) * 256 + c]     * (1.f - wx) * wy;
      if (okx1 && oky1) s += ii[((size_t)(yi + 1) * Wf + xi + 1) * 256 + c] * wx * wy;
      acc += sign * s;
    }
    vox[(size_t)n * KOFT + z * 256 + c] = f2bf(acc * inv);
  }
}

// ---------------- B^T MFMA GEMM: out[oc][n] = relu(alpha*acc + beta) -------
// A [Npad][K] bf16 row-major; B [256][K] bf16 (k-minor); block = 4 waves,
// wave = 16n x 64oc via 4 accumulators; grid = (Npad/64, 4).
// F32OUT: write float, else bf16.
template <bool F32OUT>
__global__ __launch_bounds__(256) void k_gemm(
    const unsigned short* __restrict__ A, const unsigned short* __restrict__ B,
    const float* __restrict__ alpha, const float* __restrict__ beta,
    void* __restrict__ outv, int K, int Nout) {
  int tid = threadIdx.x;
  int wave = tid >> 6, lane = tid & 63;
  int l15 = lane & 15, quad = lane >> 4;
  int n0 = blockIdx.x * 64 + wave * 16;
  int oc0 = blockIdx.y * 64;
  const short8* Ap  = (const short8*)(A + (size_t)(n0 + l15) * K + quad * 8);
  const short8* Bp0 = (const short8*)(B + (size_t)(oc0 +  0 + l15) * K + quad * 8);
  const short8* Bp1 = (const short8*)(B + (size_t)(oc0 + 16 + l15) * K + quad * 8);
  const short8* Bp2 = (const short8*)(B + (size_t)(oc0 + 32 + l15) * K + quad * 8);
  const short8* Bp3 = (const short8*)(B + (size_t)(oc0 + 48 + l15) * K + quad * 8);
  float4v acc0 = {0.f, 0.f, 0.f, 0.f};
  float4v acc1 = acc0, acc2 = acc0, acc3 = acc0;
  int steps = K >> 5;
  for (int s = 0; s < steps; ++s) {
    short8 a  = Ap[s * 4];
    short8 b0 = Bp0[s * 4];
    short8 b1 = Bp1[s * 4];
    short8 b2 = Bp2[s * 4];
    short8 b3 = Bp3[s * 4];
    acc0 = __builtin_amdgcn_mfma_f32_16x16x32_bf16(a, b0, acc0, 0, 0, 0);
    acc1 = __builtin_amdgcn_mfma_f32_16x16x32_bf16(a, b1, acc1, 0, 0, 0);
    acc2 = __builtin_amdgcn_mfma_f32_16x16x32_bf16(a, b2, acc2, 0, 0, 0);
    acc3 = __builtin_amdgcn_mfma_f32_16x16x32_bf16(a, b3, acc3, 0, 0, 0);
  }
  int nn = n0 + quad * 4;         // D row = A's m = (lane>>4)*4 + reg
  if (nn >= Nout) return;         // Nout % 4 == 0, groups all-in/all-out
  float4v accs[4] = {acc0, acc1, acc2, acc3};
#pragma unroll
  for (int t = 0; t < 4; ++t) {
    int oc = oc0 + t * 16 + l15;  // D col = B's n = lane&15
    float al = alpha[oc], be = beta[oc];
    if (F32OUT) {
      float4v r;
#pragma unroll
      for (int j = 0; j < 4; ++j) {
        float v = accs[t][j] * al + be;
        r[j] = v > 0.f ? v : 0.f;
      }
      *(float4v*)((float*)outv + (size_t)oc * Nout + nn) = r;
    } else {
      ushort4v r;
#pragma unroll
      for (int j = 0; j < 4; ++j) {
        float v = accs[t][j] * al + be;
        r[j] = f2bf(v > 0.f ? v : 0.f);
      }
      *(ushort4v*)((unsigned short*)outv + (size_t)oc * Nout + nn) = r;
    }
  }
}

// ---------------- attention: per-channel spatial mean ----------------------
__global__ void k_means(const unsigned short* __restrict__ x, float* __restrict__ means) {
  __shared__ float red[256];
  int ch = blockIdx.x, tid = threadIdx.x;
  const unsigned short* row = x + (size_t)ch * NBOX;
  float s = 0.f;
  for (int i = tid; i < NBOX; i += 256) s += bf2f(row[i]);
  red[tid] = s; __syncthreads();
  for (int off = 128; off > 0; off >>= 1) {
    if (tid < off) red[tid] += red[tid + off];
    __syncthreads();
  }
  if (tid == 0) means[ch] = red[0] / (float)NBOX;
}

__global__ void k_att(const float* __restrict__ means, const float* __restrict__ aw,
                      const float* __restrict__ ab, float* __restrict__ satt) {
  int sc = blockIdx.x, c = threadIdx.x;
  __shared__ float m[256];
  m[c] = means[sc * 256 + c]; __syncthreads();
  float acc = ab[c];
  for (int j = 0; j < 256; ++j) acc += m[j] * aw[c * 256 + j];
  satt[sc * 256 + c] = 1.f / (1.f + expf(-acc));
}

__global__ void k_scale(unsigned short* __restrict__ x, const float* __restrict__ satt) {
  int n = blockIdx.x * 256 + threadIdx.x;
  int ch = blockIdx.y;
  if (n < NBOX) {
    size_t i = (size_t)ch * NBOX + n;
    x[i] = f2bf(bf2f(x[i]) * satt[ch]);
  }
}

// ---------------- im2col for conv1 (stride 2, pad 1) -----------------------
// x stored [ic][d=108][wj=124]; ref conv H-dim = wj (ky), W-dim = d (kx).
__global__ void k_im2col1(const unsigned short* __restrict__ x, unsigned short* __restrict__ A) {
  int k = blockIdx.x * 256 + threadIdx.x;   // < 11520
  int p = blockIdx.y;                        // < 3392
  unsigned short val = 0;
  if (p < NPIX) {
    int oy = p / 54, ox = p % 54;
    int ic = k / 9, r = k % 9;
    int ky = r / 3, kx = r % 3;
    int ih = 2 * oy + ky - 1;                // wj-dim, [0,124)
    int iw = 2 * ox + kx - 1;                // d-dim,  [0,108)
    if (ih >= 0 && ih < 124 && iw >= 0 && iw < 108)
      val = x[(size_t)ic * NBOX + (size_t)iw * 124 + ih];
  }
  A[(size_t)p * KCONV1 + k] = val;
}

// ---------------- im2col for conv2 (stride 1, pad 1) -----------------------
__global__ void k_im2col2(const unsigned short* __restrict__ y, unsigned short* __restrict__ A) {
  int k = blockIdx.x * 256 + threadIdx.x;   // < 2304
  int p = blockIdx.y;                        // < 3392
  unsigned short val = 0;
  if (p < NPIX) {
    int oy = p / 54, ox = p % 54;
    int ic = k / 9, r = k % 9;
    int ky = r / 3, kx = r % 3;
    int ih = oy + ky - 1;
    int iw = ox + kx - 1;
    if (ih >= 0 && ih < 62 && iw >= 0 && iw < 54)
      val = y[(size_t)ic * NPIX + (size_t)ih * 54 + iw];
  }
  A[(size_t)p * KOFT + k] = val;
}

extern "C" void kernel_launch(void* const* d_in, const int* in_sizes, int n_in,
                              void* d_out, int out_size, void* d_ws, size_t ws_size,
                              hipStream_t stream) {
  const float* feats[5];
  for (int i = 0; i < 5; ++i) feats[i] = (const float*)d_in[i];
  const float* calib   = (const float*)d_in[5];
  const float* oft_w   = (const float*)d_in[6];
  const float* oft_b   = (const float*)d_in[7];
  const float* att_w   = (const float*)d_in[8];
  const float* att_b   = (const float*)d_in[9];
  const float* conv1_w = (const float*)d_in[10];
  const float* bn1g = (const float*)d_in[11];
  const float* bn1b = (const float*)d_in[12];
  const float* bn1m = (const float*)d_in[13];
  const float* bn1v = (const float*)d_in[14];
  const float* conv2_w = (const float*)d_in[15];
  const float* bn2g = (const float*)d_in[16];
  const float* bn2b = (const float*)d_in[17];
  const float* bn2m = (const float*)d_in[18];
  const float* bn2v = (const float*)d_in[19];

  char* ws = (char*)d_ws;
  size_t off = 0;
  auto alloc = [&](size_t bytes) -> void* {
    void* p = ws + off; off += (bytes + 255) & ~(size_t)255; return p;
  };
  float*          BBOX  = (float*)alloc((size_t)ZC * NBOX * 4 * 4);
  unsigned short* WPERM = (unsigned short*)alloc((size_t)5 * 256 * KOFT * 2);
  unsigned short* WC1   = (unsigned short*)alloc((size_t)256 * KCONV1 * 2);
  unsigned short* WC2   = (unsigned short*)alloc((size_t)256 * KOFT * 2);
  float*          II    = (float*)alloc((size_t)10475520 * 4);
  unsigned short* ABUF  = (unsigned short*)alloc((size_t)NPAD_CONV * KCONV1 * 2); // max layout
  unsigned short* XBUF  = (unsigned short*)alloc((size_t)1280 * NBOX * 2);
  unsigned short* Y1    = (unsigned short*)alloc((size_t)256 * NPIX * 2);
  float*          MEANS = (float*)alloc(1280 * 4);
  float*          SATT  = (float*)alloc(1280 * 4);
  float*          ALPHA = (float*)alloc(7 * 256 * 4);
  float*          BETA  = (float*)alloc(7 * 256 * 4);
  (void)ws_size; (void)in_sizes; (void)n_in; (void)out_size;

  static const int HFs[5] = {96, 48, 24, 12, 6};
  static const int WFs[5] = {320, 160, 80, 40, 20};
  static const size_t IIoff[5] = {0, 7864320, 9830400, 10321920, 10444800};

  k_alpha_beta<<<7, 256, 0, stream>>>(oft_b, bn1g, bn1b, bn1m, bn1v,
                                      bn2g, bn2b, bn2m, bn2v, ALPHA, BETA);
  k_wperm<<<11520, 256, 0, stream>>>(oft_w, WPERM);
  k_cvt<<<11520, 256, 0, stream>>>(conv1_w, WC1);   // 256*11520
  k_cvt<<<2304, 256, 0, stream>>>(conv2_w, WC2);    // 256*2304
  k_bbox<<<(ZC * NBOX + 255) / 256, 256, 0, stream>>>(calib, BBOX);
  k_zeropad<<<432, 256, 0, stream>>>(ABUF);         // 48*2304 pad rows of vox

  for (int s = 0; s < 5; ++s) {
    k_rowsum<<<HFs[s], 256, 0, stream>>>(feats[s], II + IIoff[s], HFs[s], WFs[s]);
    k_colsum<<<WFs[s], 256, 0, stream>>>(II + IIoff[s], HFs[s], WFs[s]);
  }
  for (int s = 0; s < 5; ++s) {
    k_sample<<<NBOX, 256, 0, stream>>>(II + IIoff[s], BBOX, ABUF, HFs[s], WFs[s],
                                       (float)(HFs[s] * WFs[s]) * 0.25f);
    k_gemm<false><<<dim3(NPAD_OFT / 64, 4), 256, 0, stream>>>(
        ABUF, WPERM + (size_t)s * 256 * KOFT,
        ALPHA + s * 256, BETA + s * 256,
        XBUF + (size_t)s * 256 * NBOX, KOFT, NBOX);
  }
  k_means<<<1280, 256, 0, stream>>>(XBUF, MEANS);
  k_att<<<5, 256, 0, stream>>>(MEANS, att_w, att_b, SATT);
  k_scale<<<dim3((NBOX + 255) / 256, 1280), 256, 0, stream>>>(XBUF, SATT);

  k_im2col1<<<dim3(KCONV1 / 256, NPAD_CONV), 256, 0, stream>>>(XBUF, ABUF);
  k_gemm<false><<<dim3(NPAD_CONV / 64, 4), 256, 0, stream>>>(
      ABUF, WC1, ALPHA + 5 * 256, BETA + 5 * 256, Y1, KCONV1, NPIX);

  k_im2col2<<<dim3(KOFT / 256, NPAD_CONV), 256, 0, stream>>>(Y1, ABUF);
  k_gemm<true><<<dim3(NPAD_CONV / 64, 4), 256, 0, stream>>>(
      ABUF, WC2, ALPHA + 6 * 256, BETA + 6 * 256,
      d_out, KOFT, NPIX);
}

// Round 3
// 1918.046 us; speedup vs baseline: 1.3413x; 1.3413x over previous
//
#include <hip/hip_runtime.h>

typedef __attribute__((ext_vector_type(8))) short short8;
typedef __attribute__((ext_vector_type(4))) float float4v;
typedef __attribute__((ext_vector_type(4))) unsigned short ushort4v;

#define NBOX 13392   // 108*124 bev cells (n = d*124 + wj)
#define ZC 9
#define KOFT 2304    // 9*256, k = z*256+c
#define NPAD_OFT 13440
#define NPIX 3348    // 62*54
#define NPAD_CONV 3392
#define KCONV1 11520 // 9*1280, k = r*1280+ic
#define KCONV2 2304  // 9*256,  k = r*256+ic

__device__ __forceinline__ unsigned short f2bf(float f) {
  union { float f; unsigned int i; } v; v.f = f;
  unsigned int r = v.i + 0x7FFFu + ((v.i >> 16) & 1u);
  return (unsigned short)(r >> 16);
}
__device__ __forceinline__ float bf2f(unsigned short u) {
  union { unsigned int i; float f; } v; v.i = ((unsigned int)u) << 16; return v.f;
}

// ---------------- alpha/beta epilogue constants + zero MEANS ---------------
__global__ void k_alpha_beta(const float* __restrict__ oft_b,
                             const float* __restrict__ g1, const float* __restrict__ b1,
                             const float* __restrict__ m1, const float* __restrict__ v1,
                             const float* __restrict__ g2, const float* __restrict__ b2,
                             const float* __restrict__ m2, const float* __restrict__ v2,
                             float* __restrict__ ALPHA, float* __restrict__ BETA,
                             float* __restrict__ MEANS) {
  int g = blockIdx.x, c = threadIdx.x;
  float al, be;
  if (g < 5) { al = 1.f; be = oft_b[g * 256 + c]; MEANS[g * 256 + c] = 0.f; }
  else {
    const float* gg = (g == 5) ? g1 : g2;
    const float* bb = (g == 5) ? b1 : b2;
    const float* mm = (g == 5) ? m1 : m2;
    const float* vv = (g == 5) ? v1 : v2;
    al = gg[c] / sqrtf(vv[c] + 1e-5f);
    be = bb[c] - mm[c] * al;
  }
  ALPHA[g * 256 + c] = al; BETA[g * 256 + c] = be;
}

// ---------------- permute oft weights: k = c*9+z -> k' = z*256+c -----------
__global__ void k_wperm(const float* __restrict__ w, unsigned short* __restrict__ wp) {
  int idx = blockIdx.x * 256 + threadIdx.x;  // < 5*256*2304
  int kp = idx % KOFT;
  int soc = idx / KOFT;
  int z = kp >> 8, c = kp & 255;
  wp[idx] = f2bf(w[(size_t)soc * KOFT + c * 9 + z]);
}

// ---------------- conv1 weights -> k'=r*1280+ic, scaled by satt[ic] --------
__global__ void k_wperm1s(const float* __restrict__ w, const float* __restrict__ satt,
                          unsigned short* __restrict__ wp) {
  int idx = blockIdx.x * 256 + threadIdx.x;  // < 256*11520
  int oc = idx / KCONV1, k = idx % KCONV1;
  int r = k / 1280, ic = k % 1280;
  wp[idx] = f2bf(w[(size_t)oc * KCONV1 + ic * 9 + r] * satt[ic]);
}

// ---------------- conv2 weights -> k'=r*256+ic -----------------------------
__global__ void k_wperm2(const float* __restrict__ w, unsigned short* __restrict__ wp) {
  int idx = blockIdx.x * 256 + threadIdx.x;  // < 256*2304
  int oc = idx / KCONV2, k = idx % KCONV2;
  int r = k / 256, ic = k % 256;
  wp[idx] = f2bf(w[(size_t)oc * KCONV2 + ic * 9 + r]);
}

// ---------------- bbox projection (scale-independent) ----------------------
__global__ void k_bbox(const float* __restrict__ calib, float* __restrict__ bbox) {
  int idx = blockIdx.x * 256 + threadIdx.x;
  if (idx >= ZC * NBOX) return;
  int z = idx / NBOX, n = idx % NBOX;
  int d = n / 124, wj = n % 124;
  float P[12];
#pragma unroll
  for (int i = 0; i < 12; ++i) P[i] = calib[i];
  auto proj = [&](int k, int i, int j, float& nx, float& ny) {
    float X = 0.64f * (float)i;
    float Y = 39.68f - 0.64f * (float)j;
    float Z = 2.76f - 0.64f * (float)k;
    float hx = P[0] * X + P[1] * Y + P[2]  * Z + P[3];
    float hy = P[4] * X + P[5] * Y + P[6]  * Z + P[7];
    float hz = P[8] * X + P[9] * Y + P[10] * Z + P[11];
    float px = hx / hz, py = hy / hz;
    nx = 2.f * px / 1280.f - 1.f; nx = fminf(fmaxf(nx, -1.f), 1.f);
    ny = 2.f * py / 384.f  - 1.f; ny = fminf(fmaxf(ny, -1.f), 1.f);
  };
  float ax, ay, bx, by, cx, cy, dx, dy;
  proj(z,     d,     wj,     ax, ay);
  proj(z,     d + 1, wj,     bx, by);
  proj(z + 1, d + 1, wj + 1, cx, cy);
  proj(z + 1, d,     wj + 1, dx, dy);
  float4v o;
  o[0] = fminf(ax, bx); o[1] = fminf(ay, by);
  o[2] = fmaxf(cx, dx); o[3] = fmaxf(cy, dy);
  *(float4v*)(bbox + (size_t)idx * 4) = o;
}

// ---------------- zero the vox pad rows ------------------------------------
__global__ void k_zeropad(unsigned short* __restrict__ A) {
  int idx = blockIdx.x * 256 + threadIdx.x;   // grid sized exactly 48*2304
  A[(size_t)NBOX * KOFT + idx] = 0;
}

// ---------------- feats [256][S] f32 -> II [S][256] f32 (LDS transpose) ----
__global__ void k_transpose(const float* __restrict__ src, float* __restrict__ dst, int S) {
  __shared__ float tile[64][65];
  int t = threadIdx.x;
  int wave = t >> 6, lane = t & 63;
  int s0 = blockIdx.x * 64, c0 = blockIdx.y * 64;
#pragma unroll
  for (int i = 0; i < 16; ++i) {
    int c_l = wave * 16 + i;
    if (s0 + lane < S) tile[c_l][lane] = src[(size_t)(c0 + c_l) * S + s0 + lane];
  }
  __syncthreads();
#pragma unroll
  for (int i = 0; i < 16; ++i) {
    int s_l = wave * 16 + i;
    if (s0 + s_l < S) dst[(size_t)(s0 + s_l) * 256 + c0 + lane] = tile[lane][s_l];
  }
}

// ---------------- cumsum over w: ii [h][w][c], coalesced -------------------
__global__ void k_cumw(float* __restrict__ ii, int Wf) {
  int c = threadIdx.x, h = blockIdx.x;
  float* p = ii + (size_t)h * Wf * 256 + c;
  float acc = 0.f;
  for (int w = 0; w < Wf; ++w) { acc += p[(size_t)w * 256]; p[(size_t)w * 256] = acc; }
}

// ---------------- cumsum over h: ii [h][w][c], coalesced -------------------
__global__ void k_cumh(float* __restrict__ ii, int Hf, int Wf) {
  int c = threadIdx.x, w = blockIdx.x;
  float* p = ii + (size_t)w * 256 + c;
  size_t stride = (size_t)Wf * 256;
  float acc = 0.f;
  for (int h = 0; h < Hf; ++h) { acc += p[h * stride]; p[h * stride] = acc; }
}

// ---------------- box sampler: wave = one n, lane = 4 channels -------------
__global__ void k_sample(const float* __restrict__ ii, const float* __restrict__ bbox,
                         unsigned short* __restrict__ vox, int Hf, int Wf, float areaScale) {
  int wave = threadIdx.x >> 6, lane = threadIdx.x & 63;
  int n = blockIdx.x * 4 + wave;
  int c4 = lane * 4;
  const float* base = ii + c4;
  for (int z = 0; z < ZC; ++z) {
    float4v bb = *(const float4v*)(bbox + ((size_t)z * NBOX + n) * 4);
    float x0 = bb[0], y0 = bb[1], x1 = bb[2], y1 = bb[3];
    float rawA = (x1 - x0) * (y1 - y0) * areaScale;
    ushort4v o;
    if (rawA > 0.f) {   // wave-uniform; degenerate boxes -> visible=0 -> zeros
      float inv = 1.f / (rawA + 1e-6f);
      float4v acc = {0.f, 0.f, 0.f, 0.f};
#pragma unroll
      for (int pt = 0; pt < 4; ++pt) {
        float gx = (pt == 0 || pt == 3) ? x0 : x1;
        float gy = (pt == 0 || pt == 2) ? y0 : y1;
        float sign = (pt < 2) ? 1.f : -1.f;
        float u = (gx + 1.f) * ((float)Wf * 0.5f) - 0.5f;
        float v = (gy + 1.f) * ((float)Hf * 0.5f) - 0.5f;
        float uf = floorf(u), vf = floorf(v);
        float wx = u - uf, wy = v - vf;
        int xi = (int)uf, yi = (int)vf;
        bool okx0 = (xi >= 0) && (xi < Wf);
        bool okx1 = (xi + 1 >= 0) && (xi + 1 < Wf);
        bool oky0 = (yi >= 0) && (yi < Hf);
        bool oky1 = (yi + 1 >= 0) && (yi + 1 < Hf);
        float w00 = sign * (1.f - wx) * (1.f - wy);
        float w01 = sign * wx * (1.f - wy);
        float w10 = sign * (1.f - wx) * wy;
        float w11 = sign * wx * wy;
        if (okx0 && oky0) acc += (*(const float4v*)(base + ((size_t)yi * Wf + xi) * 256)) * w00;
        if (okx1 && oky0) acc += (*(const float4v*)(base + ((size_t)yi * Wf + xi + 1) * 256)) * w01;
        if (okx0 && oky1) acc += (*(const float4v*)(base + ((size_t)(yi + 1) * Wf + xi) * 256)) * w10;
        if (okx1 && oky1) acc += (*(const float4v*)(base + ((size_t)(yi + 1) * Wf + xi + 1) * 256)) * w11;
      }
#pragma unroll
      for (int j = 0; j < 4; ++j) o[j] = f2bf(acc[j] * inv);
    } else {
      o[0] = 0; o[1] = 0; o[2] = 0; o[3] = 0;
    }
    *(ushort4v*)(vox + (size_t)n * KOFT + z * 256 + c4) = o;
  }
}

// ---------------- unified MFMA GEMM ----------------------------------------
// MODE 0: OFT  — A = vox [13440][2304] (pad zeroed), out = XBUF [n][1280] bf16 @ choff
// MODE 1: conv1 — implicit 3x3 s2 gather from XBUF [sp][1280], B k'=r*1280+ic, out Y1 [p][256] bf16
// MODE 2: conv2 — implicit 3x3 s1 gather from Y1 [sp][256],  B k'=r*256+ic,  out d_out [oc][3348] f32
template <int MODE, int NFRAG>
__global__ __launch_bounds__(256) void k_mm(
    const unsigned short* __restrict__ A, const unsigned short* __restrict__ B,
    const float* __restrict__ alpha, const float* __restrict__ beta,
    void* __restrict__ outv, int choff) {
  constexpr int KIC  = (MODE == 0) ? 2304 : (MODE == 1 ? 1280 : 256);
  constexpr int RMAX = (MODE == 0) ? 1 : 9;
  constexpr int BSTR = (MODE == 0) ? 2304 : (MODE == 1 ? 11520 : 2304);
  constexpr int NVAL = (MODE == 0) ? NBOX : NPIX;
  constexpr int OSTR = (MODE == 0) ? 1280 : 256;
  int tid = threadIdx.x;
  int wave = tid >> 6, lane = tid & 63;
  int l15 = lane & 15, quad = lane >> 4;
  int n0 = blockIdx.x * 64 + wave * 16;
  int oc0 = blockIdx.y * (NFRAG * 16);
  int arow = n0 + l15;
  const short8* Bp[NFRAG];
#pragma unroll
  for (int t = 0; t < NFRAG; ++t)
    Bp[t] = (const short8*)(B + (size_t)(oc0 + t * 16 + l15) * BSTR + quad * 8);
  float4v acc[NFRAG];
#pragma unroll
  for (int t = 0; t < NFRAG; ++t) acc[t] = (float4v){0.f, 0.f, 0.f, 0.f};

  for (int r = 0; r < RMAX; ++r) {
    const short8* Ap;
    bool valid;
    if (MODE == 0) {
      valid = true;
      Ap = (const short8*)(A + (size_t)arow * 2304 + quad * 8);
    } else {
      int p = arow;
      int oy = p / 54, ox = p % 54;
      int ky = r / 3, kx = r % 3;
      int sp;
      if (MODE == 1) {
        int ih = 2 * oy + ky - 1, iw = 2 * ox + kx - 1;   // ih over wj[0,124), iw over d[0,108)
        valid = (p < NVAL) && (ih >= 0) && (ih < 124) && (iw >= 0) && (iw < 108);
        sp = iw * 124 + ih;
      } else {
        int ih = oy + ky - 1, iw = ox + kx - 1;
        valid = (p < NVAL) && (ih >= 0) && (ih < 62) && (iw >= 0) && (iw < 54);
        sp = ih * 54 + iw;
      }
      Ap = (const short8*)(A + (size_t)(valid ? sp : 0) * KIC + quad * 8);
    }
    const int bofs = r * (KIC / 8);
    constexpr int STEPS = KIC / 32;
    for (int s = 0; s < STEPS; ++s) {
      short8 a;
      if (MODE != 0 && !valid) a = (short8){0, 0, 0, 0, 0, 0, 0, 0};
      else a = Ap[s * 4];
#pragma unroll
      for (int t = 0; t < NFRAG; ++t) {
        short8 b = Bp[t][bofs + s * 4];
        acc[t] = __builtin_amdgcn_mfma_f32_16x16x32_bf16(a, b, acc[t], 0, 0, 0);
      }
    }
  }

  float al[NFRAG], be[NFRAG];
#pragma unroll
  for (int t = 0; t < NFRAG; ++t) {
    int oc = oc0 + t * 16 + l15;
    al[t] = alpha[oc]; be[t] = beta[oc];
  }
  int nbase = n0 + quad * 4;
  if (MODE == 2) {
    if (nbase < NVAL) {  // NVAL%4==0 -> whole group in/out
#pragma unroll
      for (int t = 0; t < NFRAG; ++t) {
        int oc = oc0 + t * 16 + l15;
        float4v rr;
#pragma unroll
        for (int j = 0; j < 4; ++j) {
          float v = acc[t][j] * al[t] + be[t];
          rr[j] = v > 0.f ? v : 0.f;
        }
        *(float4v*)((float*)outv + (size_t)oc * NPIX + nbase) = rr;
      }
    }
  } else {
    unsigned short* ob = (unsigned short*)outv;
#pragma unroll
    for (int j = 0; j < 4; ++j) {
      int nn = nbase + j;
      if (nn < NVAL) {
#pragma unroll
        for (int t = 0; t < NFRAG; ++t) {
          int oc = oc0 + t * 16 + l15;
          float v = acc[t][j] * al[t] + be[t];
          v = v > 0.f ? v : 0.f;
          ob[(size_t)nn * OSTR + choff + oc] = f2bf(v);
        }
      }
    }
  }
}

// ---------------- channel means over XBUF [n][1280] ------------------------
__global__ void k_means2(const unsigned short* __restrict__ x, float* __restrict__ means) {
  int tid = threadIdx.x;
  int r0 = blockIdx.x * 64;
  float part[5] = {0.f, 0.f, 0.f, 0.f, 0.f};
  for (int i = 0; i < 64; ++i) {
    int row = r0 + i;
    if (row < NBOX) {
      const unsigned short* rp = x + (size_t)row * 1280;
#pragma unroll
      for (int g = 0; g < 5; ++g) part[g] += bf2f(rp[g * 256 + tid]);
    }
  }
#pragma unroll
  for (int g = 0; g < 5; ++g) atomicAdd(&means[g * 256 + tid], part[g]);
}

__global__ void k_att(const float* __restrict__ means, const float* __restrict__ aw,
                      const float* __restrict__ ab, float* __restrict__ satt) {
  int sc = blockIdx.x, c = threadIdx.x;
  __shared__ float m[256];
  m[c] = means[sc * 256 + c] * (1.f / (float)NBOX);
  __syncthreads();
  float acc = ab[c];
  for (int j = 0; j < 256; ++j) acc += m[j] * aw[c * 256 + j];
  satt[sc * 256 + c] = 1.f / (1.f + expf(-acc));
}

extern "C" void kernel_launch(void* const* d_in, const int* in_sizes, int n_in,
                              void* d_out, int out_size, void* d_ws, size_t ws_size,
                              hipStream_t stream) {
  const float* feats[5];
  for (int i = 0; i < 5; ++i) feats[i] = (const float*)d_in[i];
  const float* calib   = (const float*)d_in[5];
  const float* oft_w   = (const float*)d_in[6];
  const float* oft_b   = (const float*)d_in[7];
  const float* att_w   = (const float*)d_in[8];
  const float* att_b   = (const float*)d_in[9];
  const float* conv1_w = (const float*)d_in[10];
  const float* bn1g = (const float*)d_in[11];
  const float* bn1b = (const float*)d_in[12];
  const float* bn1m = (const float*)d_in[13];
  const float* bn1v = (const float*)d_in[14];
  const float* conv2_w = (const float*)d_in[15];
  const float* bn2g = (const float*)d_in[16];
  const float* bn2b = (const float*)d_in[17];
  const float* bn2m = (const float*)d_in[18];
  const float* bn2v = (const float*)d_in[19];

  char* ws = (char*)d_ws;
  size_t off = 0;
  auto alloc = [&](size_t bytes) -> void* {
    void* p = ws + off; off += (bytes + 255) & ~(size_t)255; return p;
  };
  float*          BBOX  = (float*)alloc((size_t)ZC * NBOX * 4 * 4);
  unsigned short* WPERM = (unsigned short*)alloc((size_t)5 * 256 * KOFT * 2);
  unsigned short* WC1S  = (unsigned short*)alloc((size_t)256 * KCONV1 * 2);
  unsigned short* WC2P  = (unsigned short*)alloc((size_t)256 * KCONV2 * 2);
  float*          II    = (float*)alloc((size_t)10475520 * 4);
  unsigned short* VOX   = (unsigned short*)alloc((size_t)NPAD_OFT * KOFT * 2);
  unsigned short* XBUF  = (unsigned short*)alloc((size_t)NBOX * 1280 * 2);
  unsigned short* Y1    = (unsigned short*)alloc((size_t)NPIX * 256 * 2);
  float*          MEANS = (float*)alloc(1280 * 4);
  float*          SATT  = (float*)alloc(1280 * 4);
  float*          ALPHA = (float*)alloc(7 * 256 * 4);
  float*          BETA  = (float*)alloc(7 * 256 * 4);
  (void)ws_size; (void)in_sizes; (void)n_in; (void)out_size;

  static const int HFs[5] = {96, 48, 24, 12, 6};
  static const int WFs[5] = {320, 160, 80, 40, 20};
  static const size_t IIoff[5] = {0, 7864320, 9830400, 10321920, 10444800};

  k_alpha_beta<<<7, 256, 0, stream>>>(oft_b, bn1g, bn1b, bn1m, bn1v,
                                      bn2g, bn2b, bn2m, bn2v, ALPHA, BETA, MEANS);
  k_wperm<<<11520, 256, 0, stream>>>(oft_w, WPERM);
  k_wperm2<<<2304, 256, 0, stream>>>(conv2_w, WC2P);
  k_bbox<<<(ZC * NBOX + 255) / 256, 256, 0, stream>>>(calib, BBOX);
  k_zeropad<<<432, 256, 0, stream>>>(VOX);

  for (int s = 0; s < 5; ++s) {
    int S = HFs[s] * WFs[s];
    k_transpose<<<dim3((S + 63) / 64, 4), 256, 0, stream>>>(feats[s], II + IIoff[s], S);
    k_cumw<<<HFs[s], 256, 0, stream>>>(II + IIoff[s], WFs[s]);
    k_cumh<<<WFs[s], 256, 0, stream>>>(II + IIoff[s], HFs[s], WFs[s]);
  }
  for (int s = 0; s < 5; ++s) {
    k_sample<<<NBOX / 4, 256, 0, stream>>>(II + IIoff[s], BBOX, VOX, HFs[s], WFs[s],
                                           (float)(HFs[s] * WFs[s]) * 0.25f);
    k_mm<0, 8><<<dim3(NPAD_OFT / 64, 2), 256, 0, stream>>>(
        VOX, WPERM + (size_t)s * 256 * KOFT,
        ALPHA + s * 256, BETA + s * 256, XBUF, s * 256);
  }
  k_means2<<<(NBOX + 63) / 64, 256, 0, stream>>>(XBUF, MEANS);
  k_att<<<5, 256, 0, stream>>>(MEANS, att_w, att_b, SATT);
  k_wperm1s<<<11520, 256, 0, stream>>>(conv1_w, SATT, WC1S);

  k_mm<1, 4><<<dim3(NPAD_CONV / 64, 4), 256, 0, stream>>>(
      XBUF, WC1S, ALPHA + 5 * 256, BETA + 5 * 256, Y1, 0);
  k_mm<2, 4><<<dim3(NPAD_CONV / 64, 4), 256, 0, stream>>>(
      Y1, WC2P, ALPHA + 6 * 256, BETA + 6 * 256, d_out, 0);
}

// Round 4
// 1529.502 us; speedup vs baseline: 1.6820x; 1.2540x over previous
//
#include <hip/hip_runtime.h>

typedef __attribute__((ext_vector_type(8))) short short8;
typedef __attribute__((ext_vector_type(4))) float float4v;
typedef __attribute__((ext_vector_type(4))) unsigned short ushort4v;

#define NBOX 13392   // 108*124 bev cells (n = d*124 + wj)
#define ZC 9
#define KOFT 2304    // 9*256, k = z*256+c
#define NPIX 3348    // 62*54
#define KCONV1 11520 // 9*1280, k = r*1280+ic
#define KCONV2 2304  // 9*256,  k = r*256+ic
#define NBLK0 105    // ceil(13392/128)
#define NBLKC 27     // ceil(3348/128)

__device__ __forceinline__ unsigned short f2bf(float f) {
  union { float f; unsigned int i; } v; v.f = f;
  unsigned int r = v.i + 0x7FFFu + ((v.i >> 16) & 1u);
  return (unsigned short)(r >> 16);
}
__device__ __forceinline__ float bf2f(unsigned short u) {
  union { unsigned int i; float f; } v; v.i = ((unsigned int)u) << 16; return v.f;
}

// async 16B global->LDS (wave-uniform LDS base + lane*16; global addr per-lane free)
__device__ __forceinline__ void async16(const unsigned short* g, unsigned short* l) {
  __builtin_amdgcn_global_load_lds(
      (const __attribute__((address_space(1))) unsigned int*)g,
      (__attribute__((address_space(3))) unsigned int*)l, 16, 0, 0);
}

// ---------------- alpha/beta epilogue constants + zero MEANS + zero page ---
__global__ void k_alpha_beta(const float* __restrict__ oft_b,
                             const float* __restrict__ g1, const float* __restrict__ b1,
                             const float* __restrict__ m1, const float* __restrict__ v1,
                             const float* __restrict__ g2, const float* __restrict__ b2,
                             const float* __restrict__ m2, const float* __restrict__ v2,
                             float* __restrict__ ALPHA, float* __restrict__ BETA,
                             float* __restrict__ MEANS, unsigned short* __restrict__ ZPAGE) {
  int g = blockIdx.x, c = threadIdx.x;
  float al, be;
  if (g < 5) { al = 1.f; be = oft_b[g * 256 + c]; MEANS[g * 256 + c] = 0.f; }
  else {
    const float* gg = (g == 5) ? g1 : g2;
    const float* bb = (g == 5) ? b1 : b2;
    const float* mm = (g == 5) ? m1 : m2;
    const float* vv = (g == 5) ? v1 : v2;
    al = gg[c] / sqrtf(vv[c] + 1e-5f);
    be = bb[c] - mm[c] * al;
  }
  ALPHA[g * 256 + c] = al; BETA[g * 256 + c] = be;
  if (g == 0) ZPAGE[c] = 0;
}

// ---------------- permute oft weights: k = c*9+z -> k' = z*256+c -----------
__global__ void k_wperm(const float* __restrict__ w, unsigned short* __restrict__ wp) {
  int idx = blockIdx.x * 256 + threadIdx.x;  // < 5*256*2304
  int kp = idx % KOFT;
  int soc = idx / KOFT;
  int z = kp >> 8, c = kp & 255;
  wp[idx] = f2bf(w[(size_t)soc * KOFT + c * 9 + z]);
}

// ---------------- conv1 weights -> k'=r*1280+ic, scaled by satt[ic] --------
__global__ void k_wperm1s(const float* __restrict__ w, const float* __restrict__ satt,
                          unsigned short* __restrict__ wp) {
  int idx = blockIdx.x * 256 + threadIdx.x;  // < 256*11520
  int oc = idx / KCONV1, k = idx % KCONV1;
  int r = k / 1280, ic = k % 1280;
  wp[idx] = f2bf(w[(size_t)oc * KCONV1 + ic * 9 + r] * satt[ic]);
}

// ---------------- conv2 weights -> k'=r*256+ic -----------------------------
__global__ void k_wperm2(const float* __restrict__ w, unsigned short* __restrict__ wp) {
  int idx = blockIdx.x * 256 + threadIdx.x;  // < 256*2304
  int oc = idx / KCONV2, k = idx % KCONV2;
  int r = k / 256, ic = k % 256;
  wp[idx] = f2bf(w[(size_t)oc * KCONV2 + ic * 9 + r]);
}

// ---------------- bbox projection (scale-independent) ----------------------
__global__ void k_bbox(const float* __restrict__ calib, float* __restrict__ bbox) {
  int idx = blockIdx.x * 256 + threadIdx.x;
  if (idx >= ZC * NBOX) return;
  int z = idx / NBOX, n = idx % NBOX;
  int d = n / 124, wj = n % 124;
  float P[12];
#pragma unroll
  for (int i = 0; i < 12; ++i) P[i] = calib[i];
  auto proj = [&](int k, int i, int j, float& nx, float& ny) {
    float X = 0.64f * (float)i;
    float Y = 39.68f - 0.64f * (float)j;
    float Z = 2.76f - 0.64f * (float)k;
    float hx = P[0] * X + P[1] * Y + P[2]  * Z + P[3];
    float hy = P[4] * X + P[5] * Y + P[6]  * Z + P[7];
    float hz = P[8] * X + P[9] * Y + P[10] * Z + P[11];
    float px = hx / hz, py = hy / hz;
    nx = 2.f * px / 1280.f - 1.f; nx = fminf(fmaxf(nx, -1.f), 1.f);
    ny = 2.f * py / 384.f  - 1.f; ny = fminf(fmaxf(ny, -1.f), 1.f);
  };
  float ax, ay, bx, by, cx, cy, dx, dy;
  proj(z,     d,     wj,     ax, ay);
  proj(z,     d + 1, wj,     bx, by);
  proj(z + 1, d + 1, wj + 1, cx, cy);
  proj(z + 1, d,     wj + 1, dx, dy);
  float4v o;
  o[0] = fminf(ax, bx); o[1] = fminf(ay, by);
  o[2] = fmaxf(cx, dx); o[3] = fmaxf(cy, dy);
  *(float4v*)(bbox + (size_t)idx * 4) = o;
}

// ---------------- feats [256][S] f32 -> II [S][256] f32 (LDS transpose) ----
__global__ void k_transpose(const float* __restrict__ src, float* __restrict__ dst, int S) {
  __shared__ float tile[64][65];
  int t = threadIdx.x;
  int wave = t >> 6, lane = t & 63;
  int s0 = blockIdx.x * 64, c0 = blockIdx.y * 64;
#pragma unroll
  for (int i = 0; i < 16; ++i) {
    int c_l = wave * 16 + i;
    if (s0 + lane < S) tile[c_l][lane] = src[(size_t)(c0 + c_l) * S + s0 + lane];
  }
  __syncthreads();
#pragma unroll
  for (int i = 0; i < 16; ++i) {
    int s_l = wave * 16 + i;
    if (s0 + s_l < S) dst[(size_t)(s0 + s_l) * 256 + c0 + lane] = tile[lane][s_l];
  }
}

// ---------------- cumsum over w: ii [h][w][c], coalesced -------------------
__global__ void k_cumw(float* __restrict__ ii, int Wf) {
  int c = threadIdx.x, h = blockIdx.x;
  float* p = ii + (size_t)h * Wf * 256 + c;
  float acc = 0.f;
  for (int w = 0; w < Wf; ++w) { acc += p[(size_t)w * 256]; p[(size_t)w * 256] = acc; }
}

// ---------------- cumsum over h: ii [h][w][c], coalesced -------------------
__global__ void k_cumh(float* __restrict__ ii, int Hf, int Wf) {
  int c = threadIdx.x, w = blockIdx.x;
  float* p = ii + (size_t)w * 256 + c;
  size_t stride = (size_t)Wf * 256;
  float acc = 0.f;
  for (int h = 0; h < Hf; ++h) { acc += p[h * stride]; p[h * stride] = acc; }
}

// ---------------- box sampler: wave = one n, lane = 4 channels -------------
__global__ void k_sample(const float* __restrict__ ii, const float* __restrict__ bbox,
                         unsigned short* __restrict__ vox, int Hf, int Wf, float areaScale) {
  int wave = threadIdx.x >> 6, lane = threadIdx.x & 63;
  int n = blockIdx.x * 4 + wave;
  int c4 = lane * 4;
  const float* base = ii + c4;
  for (int z = 0; z < ZC; ++z) {
    float4v bb = *(const float4v*)(bbox + ((size_t)z * NBOX + n) * 4);
    float x0 = bb[0], y0 = bb[1], x1 = bb[2], y1 = bb[3];
    float rawA = (x1 - x0) * (y1 - y0) * areaScale;
    ushort4v o;
    if (rawA > 0.f) {   // wave-uniform; degenerate boxes -> visible=0 -> zeros
      float inv = 1.f / (rawA + 1e-6f);
      float4v acc = {0.f, 0.f, 0.f, 0.f};
#pragma unroll
      for (int pt = 0; pt < 4; ++pt) {
        float gx = (pt == 0 || pt == 3) ? x0 : x1;
        float gy = (pt == 0 || pt == 2) ? y0 : y1;
        float sign = (pt < 2) ? 1.f : -1.f;
        float u = (gx + 1.f) * ((float)Wf * 0.5f) - 0.5f;
        float v = (gy + 1.f) * ((float)Hf * 0.5f) - 0.5f;
        float uf = floorf(u), vf = floorf(v);
        float wx = u - uf, wy = v - vf;
        int xi = (int)uf, yi = (int)vf;
        bool okx0 = (xi >= 0) && (xi < Wf);
        bool okx1 = (xi + 1 >= 0) && (xi + 1 < Wf);
        bool oky0 = (yi >= 0) && (yi < Hf);
        bool oky1 = (yi + 1 >= 0) && (yi + 1 < Hf);
        float w00 = sign * (1.f - wx) * (1.f - wy);
        float w01 = sign * wx * (1.f - wy);
        float w10 = sign * (1.f - wx) * wy;
        float w11 = sign * wx * wy;
        if (okx0 && oky0) acc += (*(const float4v*)(base + ((size_t)yi * Wf + xi) * 256)) * w00;
        if (okx1 && oky0) acc += (*(const float4v*)(base + ((size_t)yi * Wf + xi + 1) * 256)) * w01;
        if (okx0 && oky1) acc += (*(const float4v*)(base + ((size_t)(yi + 1) * Wf + xi) * 256)) * w10;
        if (okx1 && oky1) acc += (*(const float4v*)(base + ((size_t)(yi + 1) * Wf + xi + 1) * 256)) * w11;
      }
#pragma unroll
      for (int j = 0; j < 4; ++j) o[j] = f2bf(acc[j] * inv);
    } else {
      o[0] = 0; o[1] = 0; o[2] = 0; o[3] = 0;
    }
    *(ushort4v*)(vox + (size_t)n * KOFT + z * 256 + c4) = o;
  }
}

// ---------------- LDS-staged MFMA GEMM (m97 structure), 128x128xBK32 -------
// MODE 0: OFT  — A = VOX [13392][2304], out XBUF [n][1280] bf16 @ choff
// MODE 1: conv1 — implicit 3x3 s2 gather from XBUF [sp][1280], out Y1 [p][256] bf16
// MODE 2: conv2 — implicit 3x3 s1 gather from Y1 [sp][256], out d_out [oc][3348] f32
// LDS tile layout [kchunk4][row128][8] bf16 -> ds_read_b128 with 2-way-only conflicts.
template <int MODE>
__global__ __launch_bounds__(256, 1) void k_gemm(
    const unsigned short* __restrict__ A, const unsigned short* __restrict__ B,
    const float* __restrict__ alpha, const float* __restrict__ beta,
    void* __restrict__ outv, const unsigned short* __restrict__ zpage, int choff) {
  constexpr int KIC  = (MODE == 0) ? 2304 : (MODE == 1 ? 1280 : 256);
  constexpr int RMAX = (MODE == 0) ? 1 : 9;
  constexpr int NVAL = (MODE == 0) ? NBOX : NPIX;
  constexpr int OSTR = (MODE == 0) ? 1280 : 256;
  constexpr int KK   = KIC / 32;
  __shared__ unsigned short lsA[4096];   // [4][128][8]
  __shared__ unsigned short lsB[4096];
  int t = threadIdx.x;
  int lane = t & 63, wave = t >> 6;
  int l15 = lane & 15, quad = lane >> 4;
  int n0 = blockIdx.x * 128, oc0 = blockIdx.y * 128;
  int wrow = (wave >> 1) * 64, wcol = (wave & 1) * 64;
  int srow = t & 127, skc = t >> 7;      // staging row / k-chunk

  const unsigned short* gb = B + (size_t)(oc0 + srow) * (RMAX * KIC) + skc * 8;
  unsigned short* ldA = lsA + t * 8;
  unsigned short* ldB = lsB + t * 8;

  float4v acc[4][4];
#pragma unroll
  for (int mi = 0; mi < 4; ++mi)
#pragma unroll
    for (int ni = 0; ni < 4; ++ni) acc[mi][ni] = (float4v){0.f, 0.f, 0.f, 0.f};

  const unsigned short* ga = zpage;
  int astep = 0;
  if (MODE == 0) {
    int r = n0 + srow;
    bool valid = r < NBOX;
    ga = valid ? (A + (size_t)r * 2304 + skc * 8) : zpage;
    astep = valid ? 32 : 0;
  }

  for (int r = 0; r < RMAX; ++r) {
    if (MODE != 0) {
      int p = n0 + srow;
      int oy = p / 54, ox = p - oy * 54;
      int ky = r / 3, kx = r - ky * 3;
      bool valid; int sp;
      if (MODE == 1) {
        int ih = 2 * oy + ky - 1, iw = 2 * ox + kx - 1;
        valid = (p < NVAL) && ((unsigned)ih < 124u) && ((unsigned)iw < 108u);
        sp = iw * 124 + ih;
      } else {
        int ih = oy + ky - 1, iw = ox + kx - 1;
        valid = (p < NVAL) && ((unsigned)ih < 62u) && ((unsigned)iw < 54u);
        sp = ih * 54 + iw;
      }
      ga = valid ? (A + (size_t)sp * KIC + skc * 8) : zpage;
      astep = valid ? 32 : 0;
    }
    for (int s = 0; s < KK; ++s) {
      async16(ga, ldA);            // kc = skc
      async16(ga + 16, ldA + 2048);// kc = skc+2
      async16(gb, ldB);
      async16(gb + 16, ldB + 2048);
      ga += astep; gb += 32;
      __syncthreads();             // drains vmcnt before barrier (m97 pattern)
      short8 af[4], bf[4];
      const short8* pA = (const short8*)lsA;
      const short8* pB = (const short8*)lsB;
#pragma unroll
      for (int mi = 0; mi < 4; ++mi) af[mi] = pA[quad * 128 + wrow + mi * 16 + l15];
#pragma unroll
      for (int ni = 0; ni < 4; ++ni) bf[ni] = pB[quad * 128 + wcol + ni * 16 + l15];
#pragma unroll
      for (int mi = 0; mi < 4; ++mi)
#pragma unroll
        for (int ni = 0; ni < 4; ++ni)
          acc[mi][ni] = __builtin_amdgcn_mfma_f32_16x16x32_bf16(af[mi], bf[ni], acc[mi][ni], 0, 0, 0);
      __syncthreads();
    }
  }

  float al[4], be[4];
#pragma unroll
  for (int ni = 0; ni < 4; ++ni) {
    int oc = oc0 + wcol + ni * 16 + l15;
    al[ni] = alpha[oc]; be[ni] = beta[oc];
  }
  if (MODE == 2) {
    float* of = (float*)outv;
#pragma unroll
    for (int mi = 0; mi < 4; ++mi) {
      int nb = n0 + wrow + mi * 16 + quad * 4;
      if (nb < NVAL) {           // NPIX % 4 == 0 -> whole float4 in/out
#pragma unroll
        for (int ni = 0; ni < 4; ++ni) {
          int oc = oc0 + wcol + ni * 16 + l15;
          float4v rr;
#pragma unroll
          for (int j = 0; j < 4; ++j) {
            float v = acc[mi][ni][j] * al[ni] + be[ni];
            rr[j] = v > 0.f ? v : 0.f;
          }
          *(float4v*)(of + (size_t)oc * NPIX + nb) = rr;
        }
      }
    }
  } else {
    unsigned short* ob = (unsigned short*)outv;
#pragma unroll
    for (int mi = 0; mi < 4; ++mi) {
      int nb = n0 + wrow + mi * 16 + quad * 4;
#pragma unroll
      for (int j = 0; j < 4; ++j) {
        int nn = nb + j;
        if (nn < NVAL) {
#pragma unroll
          for (int ni = 0; ni < 4; ++ni) {
            int oc = oc0 + wcol + ni * 16 + l15;
            float v = acc[mi][ni][j] * al[ni] + be[ni];
            v = v > 0.f ? v : 0.f;
            ob[(size_t)nn * OSTR + choff + oc] = f2bf(v);
          }
        }
      }
    }
  }
}

// ---------------- channel means over XBUF [n][1280] ------------------------
__global__ void k_means2(const unsigned short* __restrict__ x, float* __restrict__ means) {
  int tid = threadIdx.x;
  int r0 = blockIdx.x * 64;
  float part[5] = {0.f, 0.f, 0.f, 0.f, 0.f};
  for (int i = 0; i < 64; ++i) {
    int row = r0 + i;
    if (row < NBOX) {
      const unsigned short* rp = x + (size_t)row * 1280;
#pragma unroll
      for (int g = 0; g < 5; ++g) part[g] += bf2f(rp[g * 256 + tid]);
    }
  }
#pragma unroll
  for (int g = 0; g < 5; ++g) atomicAdd(&means[g * 256 + tid], part[g]);
}

__global__ void k_att(const float* __restrict__ means, const float* __restrict__ aw,
                      const float* __restrict__ ab, float* __restrict__ satt) {
  int sc = blockIdx.x, c = threadIdx.x;
  __shared__ float m[256];
  m[c] = means[sc * 256 + c] * (1.f / (float)NBOX);
  __syncthreads();
  float acc = ab[c];
  for (int j = 0; j < 256; ++j) acc += m[j] * aw[c * 256 + j];
  satt[sc * 256 + c] = 1.f / (1.f + expf(-acc));
}

extern "C" void kernel_launch(void* const* d_in, const int* in_sizes, int n_in,
                              void* d_out, int out_size, void* d_ws, size_t ws_size,
                              hipStream_t stream) {
  const float* feats[5];
  for (int i = 0; i < 5; ++i) feats[i] = (const float*)d_in[i];
  const float* calib   = (const float*)d_in[5];
  const float* oft_w   = (const float*)d_in[6];
  const float* oft_b   = (const float*)d_in[7];
  const float* att_w   = (const float*)d_in[8];
  const float* att_b   = (const float*)d_in[9];
  const float* conv1_w = (const float*)d_in[10];
  const float* bn1g = (const float*)d_in[11];
  const float* bn1b = (const float*)d_in[12];
  const float* bn1m = (const float*)d_in[13];
  const float* bn1v = (const float*)d_in[14];
  const float* conv2_w = (const float*)d_in[15];
  const float* bn2g = (const float*)d_in[16];
  const float* bn2b = (const float*)d_in[17];
  const float* bn2m = (const float*)d_in[18];
  const float* bn2v = (const float*)d_in[19];

  char* ws = (char*)d_ws;
  size_t off = 0;
  auto alloc = [&](size_t bytes) -> void* {
    void* p = ws + off; off += (bytes + 255) & ~(size_t)255; return p;
  };
  float*          BBOX  = (float*)alloc((size_t)ZC * NBOX * 4 * 4);
  unsigned short* WPERM = (unsigned short*)alloc((size_t)5 * 256 * KOFT * 2);
  unsigned short* WC1S  = (unsigned short*)alloc((size_t)256 * KCONV1 * 2);
  unsigned short* WC2P  = (unsigned short*)alloc((size_t)256 * KCONV2 * 2);
  float*          II    = (float*)alloc((size_t)10475520 * 4);
  unsigned short* VOX   = (unsigned short*)alloc((size_t)NBOX * KOFT * 2);
  unsigned short* XBUF  = (unsigned short*)alloc((size_t)NBOX * 1280 * 2);
  unsigned short* Y1    = (unsigned short*)alloc((size_t)NPIX * 256 * 2);
  float*          MEANS = (float*)alloc(1280 * 4);
  float*          SATT  = (float*)alloc(1280 * 4);
  float*          ALPHA = (float*)alloc(7 * 256 * 4);
  float*          BETA  = (float*)alloc(7 * 256 * 4);
  unsigned short* ZPAGE = (unsigned short*)alloc(256 * 2);
  (void)ws_size; (void)in_sizes; (void)n_in; (void)out_size;

  static const int HFs[5] = {96, 48, 24, 12, 6};
  static const int WFs[5] = {320, 160, 80, 40, 20};
  static const size_t IIoff[5] = {0, 7864320, 9830400, 10321920, 10444800};

  k_alpha_beta<<<7, 256, 0, stream>>>(oft_b, bn1g, bn1b, bn1m, bn1v,
                                      bn2g, bn2b, bn2m, bn2v, ALPHA, BETA, MEANS, ZPAGE);
  k_wperm<<<11520, 256, 0, stream>>>(oft_w, WPERM);
  k_wperm2<<<2304, 256, 0, stream>>>(conv2_w, WC2P);
  k_bbox<<<(ZC * NBOX + 255) / 256, 256, 0, stream>>>(calib, BBOX);

  for (int s = 0; s < 5; ++s) {
    int S = HFs[s] * WFs[s];
    k_transpose<<<dim3((S + 63) / 64, 4), 256, 0, stream>>>(feats[s], II + IIoff[s], S);
    k_cumw<<<HFs[s], 256, 0, stream>>>(II + IIoff[s], WFs[s]);
    k_cumh<<<WFs[s], 256, 0, stream>>>(II + IIoff[s], HFs[s], WFs[s]);
  }
  for (int s = 0; s < 5; ++s) {
    k_sample<<<NBOX / 4, 256, 0, stream>>>(II + IIoff[s], BBOX, VOX, HFs[s], WFs[s],
                                           (float)(HFs[s] * WFs[s]) * 0.25f);
    k_gemm<0><<<dim3(NBLK0, 2), 256, 0, stream>>>(
        VOX, WPERM + (size_t)s * 256 * KOFT,
        ALPHA + s * 256, BETA + s * 256, XBUF, ZPAGE, s * 256);
  }
  k_means2<<<(NBOX + 63) / 64, 256, 0, stream>>>(XBUF, MEANS);
  k_att<<<5, 256, 0, stream>>>(MEANS, att_w, att_b, SATT);
  k_wperm1s<<<11520, 256, 0, stream>>>(conv1_w, SATT, WC1S);

  k_gemm<1><<<dim3(NBLKC, 2), 256, 0, stream>>>(
      XBUF, WC1S, ALPHA + 5 * 256, BETA + 5 * 256, Y1, ZPAGE, 0);
  k_gemm<2><<<dim3(NBLKC, 2), 256, 0, stream>>>(
      Y1, WC2P, ALPHA + 6 * 256, BETA + 6 * 256, d_out, ZPAGE, 0);
}

// Round 5
// 1468.314 us; speedup vs baseline: 1.7521x; 1.0417x over previous
//
#include <hip/hip_runtime.h>

typedef __attribute__((ext_vector_type(8))) short short8;
typedef __attribute__((ext_vector_type(4))) float float4v;
typedef __attribute__((ext_vector_type(4))) unsigned short ushort4v;

#define NBOX 13392   // 108*124 bev cells (n = d*124 + wj)
#define ZC 9
#define KOFT 2304    // 9*256, k = z*256+c
#define NPIX 3348    // 62*54
#define KCONV1 11520 // 9*1280, k = r*1280+ic
#define KCONV2 2304  // 9*256,  k = r*256+ic
#define NBLK0 105    // ceil(13392/128)
#define NBLKC 27     // ceil(3348/128)
#define TILEK 4096   // shorts per 8KB step-tile [kc4][row128][8]
#define NBSTRIDE 294912  // 72 steps * 4096 shorts per n-block / col-block

__device__ __forceinline__ unsigned short f2bf(float f) {
  union { float f; unsigned int i; } v; v.f = f;
  unsigned int r = v.i + 0x7FFFu + ((v.i >> 16) & 1u);
  return (unsigned short)(r >> 16);
}
__device__ __forceinline__ float bf2f(unsigned short u) {
  union { unsigned int i; float f; } v; v.i = ((unsigned int)u) << 16; return v.f;
}

// async 16B global->LDS (wave-uniform LDS base + lane*16)
__device__ __forceinline__ void async16(const unsigned short* g, unsigned short* l) {
  __builtin_amdgcn_global_load_lds(
      (const __attribute__((address_space(1))) unsigned int*)g,
      (__attribute__((address_space(3))) unsigned int*)l, 16, 0, 0);
}

// ---------------- alpha/beta epilogue constants + zero MEANS + zero page ---
__global__ void k_alpha_beta(const float* __restrict__ oft_b,
                             const float* __restrict__ g1, const float* __restrict__ b1,
                             const float* __restrict__ m1, const float* __restrict__ v1,
                             const float* __restrict__ g2, const float* __restrict__ b2,
                             const float* __restrict__ m2, const float* __restrict__ v2,
                             float* __restrict__ ALPHA, float* __restrict__ BETA,
                             float* __restrict__ MEANS, unsigned short* __restrict__ ZPAGE) {
  int g = blockIdx.x, c = threadIdx.x;
  float al, be;
  if (g < 5) { al = 1.f; be = oft_b[g * 256 + c]; MEANS[g * 256 + c] = 0.f; }
  else {
    const float* gg = (g == 5) ? g1 : g2;
    const float* bb = (g == 5) ? b1 : b2;
    const float* mm = (g == 5) ? m1 : m2;
    const float* vv = (g == 5) ? v1 : v2;
    al = gg[c] / sqrtf(vv[c] + 1e-5f);
    be = bb[c] - mm[c] * al;
  }
  ALPHA[g * 256 + c] = al; BETA[g * 256 + c] = be;
  if (g == 0) ZPAGE[c] = 0;
}

// ---------------- oft weights -> tiled B: [sc][cb2][s72][kc4][row128][j8] ---
__global__ void k_wpermT(const float* __restrict__ w, unsigned short* __restrict__ wp) {
  int idx = blockIdx.x * 256 + threadIdx.x;  // < 5*589824
  int sc = idx / 589824;
  int r  = idx % 589824;
  int j   = r & 7;
  int row = (r >> 3) & 127;
  int kc  = (r >> 10) & 3;
  int cs  = r >> 12;            // cb*72 + s
  int cb  = cs / 72, s = cs % 72;
  int oc = cb * 128 + row;
  int k  = s * 32 + kc * 8 + j; // k' = z*256 + c
  int z = k >> 8, c = k & 255;
  wp[idx] = f2bf(w[((size_t)sc * 256 + oc) * 2304 + c * 9 + z]);
}

// ---------------- conv1 weights -> k'=r*1280+ic, scaled by satt[ic] --------
__global__ void k_wperm1s(const float* __restrict__ w, const float* __restrict__ satt,
                          unsigned short* __restrict__ wp) {
  int idx = blockIdx.x * 256 + threadIdx.x;  // < 256*11520
  int oc = idx / KCONV1, k = idx % KCONV1;
  int r = k / 1280, ic = k % 1280;
  wp[idx] = f2bf(w[(size_t)oc * KCONV1 + ic * 9 + r] * satt[ic]);
}

// ---------------- conv2 weights -> k'=r*256+ic -----------------------------
__global__ void k_wperm2(const float* __restrict__ w, unsigned short* __restrict__ wp) {
  int idx = blockIdx.x * 256 + threadIdx.x;  // < 256*2304
  int oc = idx / KCONV2, k = idx % KCONV2;
  int r = k / 256, ic = k % 256;
  wp[idx] = f2bf(w[(size_t)oc * KCONV2 + ic * 9 + r]);
}

// ---------------- bbox projection (scale-independent) ----------------------
__global__ void k_bbox(const float* __restrict__ calib, float* __restrict__ bbox) {
  int idx = blockIdx.x * 256 + threadIdx.x;
  if (idx >= ZC * NBOX) return;
  int z = idx / NBOX, n = idx % NBOX;
  int d = n / 124, wj = n % 124;
  float P[12];
#pragma unroll
  for (int i = 0; i < 12; ++i) P[i] = calib[i];
  auto proj = [&](int k, int i, int j, float& nx, float& ny) {
    float X = 0.64f * (float)i;
    float Y = 39.68f - 0.64f * (float)j;
    float Z = 2.76f - 0.64f * (float)k;
    float hx = P[0] * X + P[1] * Y + P[2]  * Z + P[3];
    float hy = P[4] * X + P[5] * Y + P[6]  * Z + P[7];
    float hz = P[8] * X + P[9] * Y + P[10] * Z + P[11];
    float px = hx / hz, py = hy / hz;
    nx = 2.f * px / 1280.f - 1.f; nx = fminf(fmaxf(nx, -1.f), 1.f);
    ny = 2.f * py / 384.f  - 1.f; ny = fminf(fmaxf(ny, -1.f), 1.f);
  };
  float ax, ay, bx, by, cx, cy, dx, dy;
  proj(z,     d,     wj,     ax, ay);
  proj(z,     d + 1, wj,     bx, by);
  proj(z + 1, d + 1, wj + 1, cx, cy);
  proj(z + 1, d,     wj + 1, dx, dy);
  float4v o;
  o[0] = fminf(ax, bx); o[1] = fminf(ay, by);
  o[2] = fmaxf(cx, dx); o[3] = fmaxf(cy, dy);
  *(float4v*)(bbox + (size_t)idx * 4) = o;
}

// ---------------- feats [256][S] f32 -> II [S][256] f32 (LDS transpose) ----
__global__ void k_transpose(const float* __restrict__ src, float* __restrict__ dst, int S) {
  __shared__ float tile[64][65];
  int t = threadIdx.x;
  int wave = t >> 6, lane = t & 63;
  int s0 = blockIdx.x * 64, c0 = blockIdx.y * 64;
#pragma unroll
  for (int i = 0; i < 16; ++i) {
    int c_l = wave * 16 + i;
    if (s0 + lane < S) tile[c_l][lane] = src[(size_t)(c0 + c_l) * S + s0 + lane];
  }
  __syncthreads();
#pragma unroll
  for (int i = 0; i < 16; ++i) {
    int s_l = wave * 16 + i;
    if (s0 + s_l < S) dst[(size_t)(s0 + s_l) * 256 + c0 + lane] = tile[lane][s_l];
  }
}

// ---------------- cumsum over w: ii [h][w][c], coalesced -------------------
__global__ void k_cumw(float* __restrict__ ii, int Wf) {
  int c = threadIdx.x, h = blockIdx.x;
  float* p = ii + (size_t)h * Wf * 256 + c;
  float acc = 0.f;
  for (int w = 0; w < Wf; ++w) { acc += p[(size_t)w * 256]; p[(size_t)w * 256] = acc; }
}

// ---------------- cumsum over h: ii [h][w][c], coalesced -------------------
__global__ void k_cumh(float* __restrict__ ii, int Hf, int Wf) {
  int c = threadIdx.x, w = blockIdx.x;
  float* p = ii + (size_t)w * 256 + c;
  size_t stride = (size_t)Wf * 256;
  float acc = 0.f;
  for (int h = 0; h < Hf; ++h) { acc += p[h * stride]; p[h * stride] = acc; }
}

// ---------------- box sampler: wave = one n, lane = 4 channels -------------
// writes VOX in GEMM tile-ready layout [nb][s][kc][row][8]
__global__ void k_sample(const float* __restrict__ ii, const float* __restrict__ bbox,
                         unsigned short* __restrict__ voxT, int Hf, int Wf, float areaScale) {
  int wave = threadIdx.x >> 6, lane = threadIdx.x & 63;
  int n = blockIdx.x * 4 + wave;
  int c4 = lane * 4;
  const float* base = ii + c4;
  int nb = n >> 7, row = n & 127;
  // for k = z*256 + lane*4: s = z*8 + (lane>>3), kc = (lane>>1)&3, j = (lane&1)*4
  unsigned short* vb = voxT + (size_t)nb * NBSTRIDE + (size_t)row * 8
                     + (lane >> 3) * 4096 + ((lane >> 1) & 3) * 1024 + (lane & 1) * 4;
  for (int z = 0; z < ZC; ++z) {
    float4v bb = *(const float4v*)(bbox + ((size_t)z * NBOX + n) * 4);
    float x0 = bb[0], y0 = bb[1], x1 = bb[2], y1 = bb[3];
    float rawA = (x1 - x0) * (y1 - y0) * areaScale;
    ushort4v o;
    if (rawA > 0.f) {   // wave-uniform; degenerate boxes -> visible=0 -> zeros
      float inv = 1.f / (rawA + 1e-6f);
      float4v acc = {0.f, 0.f, 0.f, 0.f};
#pragma unroll
      for (int pt = 0; pt < 4; ++pt) {
        float gx = (pt == 0 || pt == 3) ? x0 : x1;
        float gy = (pt == 0 || pt == 2) ? y0 : y1;
        float sign = (pt < 2) ? 1.f : -1.f;
        float u = (gx + 1.f) * ((float)Wf * 0.5f) - 0.5f;
        float v = (gy + 1.f) * ((float)Hf * 0.5f) - 0.5f;
        float uf = floorf(u), vf = floorf(v);
        float wx = u - uf, wy = v - vf;
        int xi = (int)uf, yi = (int)vf;
        bool okx0 = (xi >= 0) && (xi < Wf);
        bool okx1 = (xi + 1 >= 0) && (xi + 1 < Wf);
        bool oky0 = (yi >= 0) && (yi < Hf);
        bool oky1 = (yi + 1 >= 0) && (yi + 1 < Hf);
        float w00 = sign * (1.f - wx) * (1.f - wy);
        float w01 = sign * wx * (1.f - wy);
        float w10 = sign * (1.f - wx) * wy;
        float w11 = sign * wx * wy;
        if (okx0 && oky0) acc += (*(const float4v*)(base + ((size_t)yi * Wf + xi) * 256)) * w00;
        if (okx1 && oky0) acc += (*(const float4v*)(base + ((size_t)yi * Wf + xi + 1) * 256)) * w01;
        if (okx0 && oky1) acc += (*(const float4v*)(base + ((size_t)(yi + 1) * Wf + xi) * 256)) * w10;
        if (okx1 && oky1) acc += (*(const float4v*)(base + ((size_t)(yi + 1) * Wf + xi + 1) * 256)) * w11;
      }
#pragma unroll
      for (int j = 0; j < 4; ++j) o[j] = f2bf(acc[j] * inv);
    } else {
      o[0] = 0; o[1] = 0; o[2] = 0; o[3] = 0;
    }
    *(ushort4v*)(vb + z * 32768) = o;
  }
}

// ---------------- OFT GEMM: tile-ready A/B, contiguous 1KB/wave staging ----
// A = VOXT [nb][72][4096], B = WPERMT [cb][72][4096]; out XBUF [n][1280] @ choff
__global__ __launch_bounds__(256, 1) void k_gemmT(
    const unsigned short* __restrict__ AT, const unsigned short* __restrict__ BT,
    const float* __restrict__ alpha, const float* __restrict__ beta,
    unsigned short* __restrict__ out, int choff) {
  __shared__ unsigned short lsA[4096];   // [kc4][row128][8]
  __shared__ unsigned short lsB[4096];
  int t = threadIdx.x;
  int lane = t & 63, wave = t >> 6;
  int l15 = lane & 15, quad = lane >> 4;
  int nb = blockIdx.x, cb = blockIdx.y;
  int wrow = (wave >> 1) * 64, wcol = (wave & 1) * 64;

  const unsigned short* ga = AT + (size_t)nb * NBSTRIDE + t * 8;
  const unsigned short* gb = BT + (size_t)cb * NBSTRIDE + t * 8;
  unsigned short* ldA = lsA + t * 8;
  unsigned short* ldB = lsB + t * 8;

  float4v acc[4][4];
#pragma unroll
  for (int mi = 0; mi < 4; ++mi)
#pragma unroll
    for (int ni = 0; ni < 4; ++ni) acc[mi][ni] = (float4v){0.f, 0.f, 0.f, 0.f};

  for (int s = 0; s < 72; ++s) {
    async16(ga, ldA);
    async16(ga + 2048, ldA + 2048);
    async16(gb, ldB);
    async16(gb + 2048, ldB + 2048);
    ga += TILEK; gb += TILEK;
    __syncthreads();
    short8 af[4], bf[4];
    const short8* pA = (const short8*)lsA;
    const short8* pB = (const short8*)lsB;
#pragma unroll
    for (int mi = 0; mi < 4; ++mi) af[mi] = pA[quad * 128 + wrow + mi * 16 + l15];
#pragma unroll
    for (int ni = 0; ni < 4; ++ni) bf[ni] = pB[quad * 128 + wcol + ni * 16 + l15];
#pragma unroll
    for (int mi = 0; mi < 4; ++mi)
#pragma unroll
      for (int ni = 0; ni < 4; ++ni)
        acc[mi][ni] = __builtin_amdgcn_mfma_f32_16x16x32_bf16(af[mi], bf[ni], acc[mi][ni], 0, 0, 0);
    __syncthreads();
  }

  float al[4], be[4];
#pragma unroll
  for (int ni = 0; ni < 4; ++ni) {
    int oc = cb * 128 + wcol + ni * 16 + l15;
    al[ni] = alpha[oc]; be[ni] = beta[oc];
  }
#pragma unroll
  for (int mi = 0; mi < 4; ++mi) {
    int nb0 = nb * 128 + wrow + mi * 16 + quad * 4;
#pragma unroll
    for (int j = 0; j < 4; ++j) {
      int nn = nb0 + j;
      if (nn < NBOX) {
#pragma unroll
        for (int ni = 0; ni < 4; ++ni) {
          int oc = cb * 128 + wcol + ni * 16 + l15;
          float v = acc[mi][ni][j] * al[ni] + be[ni];
          v = v > 0.f ? v : 0.f;
          out[(size_t)nn * 1280 + choff + oc] = f2bf(v);
        }
      }
    }
  }
}

// ---------------- conv GEMMs (implicit im2col), unchanged from r4 ----------
// MODE 1: conv1 3x3 s2 gather from XBUF [sp][1280], out Y1 [p][256] bf16
// MODE 2: conv2 3x3 s1 gather from Y1 [sp][256], out d_out [oc][3348] f32
template <int MODE>
__global__ __launch_bounds__(256, 1) void k_gemm(
    const unsigned short* __restrict__ A, const unsigned short* __restrict__ B,
    const float* __restrict__ alpha, const float* __restrict__ beta,
    void* __restrict__ outv, const unsigned short* __restrict__ zpage) {
  constexpr int KIC  = (MODE == 1) ? 1280 : 256;
  constexpr int KK   = KIC / 32;
  __shared__ unsigned short lsA[4096];
  __shared__ unsigned short lsB[4096];
  int t = threadIdx.x;
  int lane = t & 63, wave = t >> 6;
  int l15 = lane & 15, quad = lane >> 4;
  int n0 = blockIdx.x * 128, oc0 = blockIdx.y * 128;
  int wrow = (wave >> 1) * 64, wcol = (wave & 1) * 64;
  int srow = t & 127, skc = t >> 7;

  const unsigned short* gb = B + (size_t)(oc0 + srow) * (9 * KIC) + skc * 8;
  unsigned short* ldA = lsA + t * 8;
  unsigned short* ldB = lsB + t * 8;

  float4v acc[4][4];
#pragma unroll
  for (int mi = 0; mi < 4; ++mi)
#pragma unroll
    for (int ni = 0; ni < 4; ++ni) acc[mi][ni] = (float4v){0.f, 0.f, 0.f, 0.f};

  for (int r = 0; r < 9; ++r) {
    int p = n0 + srow;
    int oy = p / 54, ox = p - oy * 54;
    int ky = r / 3, kx = r - ky * 3;
    bool valid; int sp;
    if (MODE == 1) {
      int ih = 2 * oy + ky - 1, iw = 2 * ox + kx - 1;
      valid = (p < NPIX) && ((unsigned)ih < 124u) && ((unsigned)iw < 108u);
      sp = iw * 124 + ih;
    } else {
      int ih = oy + ky - 1, iw = ox + kx - 1;
      valid = (p < NPIX) && ((unsigned)ih < 62u) && ((unsigned)iw < 54u);
      sp = ih * 54 + iw;
    }
    const unsigned short* ga = valid ? (A + (size_t)sp * KIC + skc * 8) : zpage;
    int astep = valid ? 32 : 0;
    for (int s = 0; s < KK; ++s) {
      async16(ga, ldA);
      async16(ga + 16, ldA + 2048);
      async16(gb, ldB);
      async16(gb + 16, ldB + 2048);
      ga += astep; gb += 32;
      __syncthreads();
      short8 af[4], bf[4];
      const short8* pA = (const short8*)lsA;
      const short8* pB = (const short8*)lsB;
#pragma unroll
      for (int mi = 0; mi < 4; ++mi) af[mi] = pA[quad * 128 + wrow + mi * 16 + l15];
#pragma unroll
      for (int ni = 0; ni < 4; ++ni) bf[ni] = pB[quad * 128 + wcol + ni * 16 + l15];
#pragma unroll
      for (int mi = 0; mi < 4; ++mi)
#pragma unroll
        for (int ni = 0; ni < 4; ++ni)
          acc[mi][ni] = __builtin_amdgcn_mfma_f32_16x16x32_bf16(af[mi], bf[ni], acc[mi][ni], 0, 0, 0);
      __syncthreads();
    }
  }

  float al[4], be[4];
#pragma unroll
  for (int ni = 0; ni < 4; ++ni) {
    int oc = oc0 + wcol + ni * 16 + l15;
    al[ni] = alpha[oc]; be[ni] = beta[oc];
  }
  if (MODE == 2) {
    float* of = (float*)outv;
#pragma unroll
    for (int mi = 0; mi < 4; ++mi) {
      int nb = n0 + wrow + mi * 16 + quad * 4;
      if (nb < NPIX) {
#pragma unroll
        for (int ni = 0; ni < 4; ++ni) {
          int oc = oc0 + wcol + ni * 16 + l15;
          float4v rr;
#pragma unroll
          for (int j = 0; j < 4; ++j) {
            float v = acc[mi][ni][j] * al[ni] + be[ni];
            rr[j] = v > 0.f ? v : 0.f;
          }
          *(float4v*)(of + (size_t)oc * NPIX + nb) = rr;
        }
      }
    }
  } else {
    unsigned short* ob = (unsigned short*)outv;
#pragma unroll
    for (int mi = 0; mi < 4; ++mi) {
      int nb = n0 + wrow + mi * 16 + quad * 4;
#pragma unroll
      for (int j = 0; j < 4; ++j) {
        int nn = nb + j;
        if (nn < NPIX) {
#pragma unroll
          for (int ni = 0; ni < 4; ++ni) {
            int oc = oc0 + wcol + ni * 16 + l15;
            float v = acc[mi][ni][j] * al[ni] + be[ni];
            v = v > 0.f ? v : 0.f;
            ob[(size_t)nn * 256 + oc] = f2bf(v);
          }
        }
      }
    }
  }
}

// ---------------- channel means over XBUF [n][1280] ------------------------
__global__ void k_means2(const unsigned short* __restrict__ x, float* __restrict__ means) {
  int tid = threadIdx.x;
  int r0 = blockIdx.x * 64;
  float part[5] = {0.f, 0.f, 0.f, 0.f, 0.f};
  for (int i = 0; i < 64; ++i) {
    int row = r0 + i;
    if (row < NBOX) {
      const unsigned short* rp = x + (size_t)row * 1280;
#pragma unroll
      for (int g = 0; g < 5; ++g) part[g] += bf2f(rp[g * 256 + tid]);
    }
  }
#pragma unroll
  for (int g = 0; g < 5; ++g) atomicAdd(&means[g * 256 + tid], part[g]);
}

__global__ void k_att(const float* __restrict__ means, const float* __restrict__ aw,
                      const float* __restrict__ ab, float* __restrict__ satt) {
  int sc = blockIdx.x, c = threadIdx.x;
  __shared__ float m[256];
  m[c] = means[sc * 256 + c] * (1.f / (float)NBOX);
  __syncthreads();
  float acc = ab[c];
  for (int j = 0; j < 256; ++j) acc += m[j] * aw[c * 256 + j];
  satt[sc * 256 + c] = 1.f / (1.f + expf(-acc));
}

extern "C" void kernel_launch(void* const* d_in, const int* in_sizes, int n_in,
                              void* d_out, int out_size, void* d_ws, size_t ws_size,
                              hipStream_t stream) {
  const float* feats[5];
  for (int i = 0; i < 5; ++i) feats[i] = (const float*)d_in[i];
  const float* calib   = (const float*)d_in[5];
  const float* oft_w   = (const float*)d_in[6];
  const float* oft_b   = (const float*)d_in[7];
  const float* att_w   = (const float*)d_in[8];
  const float* att_b   = (const float*)d_in[9];
  const float* conv1_w = (const float*)d_in[10];
  const float* bn1g = (const float*)d_in[11];
  const float* bn1b = (const float*)d_in[12];
  const float* bn1m = (const float*)d_in[13];
  const float* bn1v = (const float*)d_in[14];
  const float* conv2_w = (const float*)d_in[15];
  const float* bn2g = (const float*)d_in[16];
  const float* bn2b = (const float*)d_in[17];
  const float* bn2m = (const float*)d_in[18];
  const float* bn2v = (const float*)d_in[19];

  char* ws = (char*)d_ws;
  size_t off = 0;
  auto alloc = [&](size_t bytes) -> void* {
    void* p = ws + off; off += (bytes + 255) & ~(size_t)255; return p;
  };
  float*          BBOX   = (float*)alloc((size_t)ZC * NBOX * 4 * 4);
  unsigned short* WPERMT = (unsigned short*)alloc((size_t)5 * 589824 * 2);
  unsigned short* WC1S   = (unsigned short*)alloc((size_t)256 * KCONV1 * 2);
  unsigned short* WC2P   = (unsigned short*)alloc((size_t)256 * KCONV2 * 2);
  float*          II     = (float*)alloc((size_t)10475520 * 4);
  unsigned short* VOXT   = (unsigned short*)alloc((size_t)NBLK0 * NBSTRIDE * 2);
  unsigned short* XBUF   = (unsigned short*)alloc((size_t)NBOX * 1280 * 2);
  unsigned short* Y1     = (unsigned short*)alloc((size_t)NPIX * 256 * 2);
  float*          MEANS  = (float*)alloc(1280 * 4);
  float*          SATT   = (float*)alloc(1280 * 4);
  float*          ALPHA  = (float*)alloc(7 * 256 * 4);
  float*          BETA   = (float*)alloc(7 * 256 * 4);
  unsigned short* ZPAGE  = (unsigned short*)alloc(256 * 2);
  (void)ws_size; (void)in_sizes; (void)n_in; (void)out_size;

  static const int HFs[5] = {96, 48, 24, 12, 6};
  static const int WFs[5] = {320, 160, 80, 40, 20};
  static const size_t IIoff[5] = {0, 7864320, 9830400, 10321920, 10444800};

  k_alpha_beta<<<7, 256, 0, stream>>>(oft_b, bn1g, bn1b, bn1m, bn1v,
                                      bn2g, bn2b, bn2m, bn2v, ALPHA, BETA, MEANS, ZPAGE);
  k_wpermT<<<11520, 256, 0, stream>>>(oft_w, WPERMT);
  k_wperm2<<<2304, 256, 0, stream>>>(conv2_w, WC2P);
  k_bbox<<<(ZC * NBOX + 255) / 256, 256, 0, stream>>>(calib, BBOX);

  for (int s = 0; s < 5; ++s) {
    int S = HFs[s] * WFs[s];
    k_transpose<<<dim3((S + 63) / 64, 4), 256, 0, stream>>>(feats[s], II + IIoff[s], S);
    k_cumw<<<HFs[s], 256, 0, stream>>>(II + IIoff[s], WFs[s]);
    k_cumh<<<WFs[s], 256, 0, stream>>>(II + IIoff[s], HFs[s], WFs[s]);
  }
  for (int s = 0; s < 5; ++s) {
    k_sample<<<NBOX / 4, 256, 0, stream>>>(II + IIoff[s], BBOX, VOXT, HFs[s], WFs[s],
                                           (float)(HFs[s] * WFs[s]) * 0.25f);
    k_gemmT<<<dim3(NBLK0, 2), 256, 0, stream>>>(
        VOXT, WPERMT + (size_t)s * 589824,
        ALPHA + s * 256, BETA + s * 256, XBUF, s * 256);
  }
  k_means2<<<(NBOX + 63) / 64, 256, 0, stream>>>(XBUF, MEANS);
  k_att<<<5, 256, 0, stream>>>(MEANS, att_w, att_b, SATT);
  k_wperm1s<<<11520, 256, 0, stream>>>(conv1_w, SATT, WC1S);

  k_gemm<1><<<dim3(NBLKC, 2), 256, 0, stream>>>(
      XBUF, WC1S, ALPHA + 5 * 256, BETA + 5 * 256, Y1, ZPAGE);
  k_gemm<2><<<dim3(NBLKC, 2), 256, 0, stream>>>(
      Y1, WC2P, ALPHA + 6 * 256, BETA + 6 * 256, d_out, ZPAGE);
}

// Round 6
// 1164.472 us; speedup vs baseline: 2.2093x; 1.2609x over previous
//
#include <hip/hip_runtime.h>

typedef __attribute__((ext_vector_type(8))) short short8;
typedef __attribute__((ext_vector_type(4))) float float4v;
typedef __attribute__((ext_vector_type(4))) unsigned short ushort4v;

#define NBOX 13392   // 108*124 bev cells (n = d*124 + wj)
#define ZC 9
#define KOFT 2304    // 9*256, k = z*256+c
#define NPIX 3348    // 62*54
#define NBLK0 105    // ceil(13392/128)
#define NBLKC 27     // ceil(3348/128)
#define TILEK 4096   // shorts per 8KB step-tile [kc4][row128][8]
#define NBSTRIDE 294912  // 72 steps * 4096 shorts per row-block / col-block
#define OFT_SPLIT 3      // 24 steps per split chunk

__device__ __forceinline__ unsigned short f2bf(float f) {
  union { float f; unsigned int i; } v; v.f = f;
  unsigned int r = v.i + 0x7FFFu + ((v.i >> 16) & 1u);
  return (unsigned short)(r >> 16);
}
__device__ __forceinline__ float bf2f(unsigned short u) {
  union { unsigned int i; float f; } v; v.i = ((unsigned int)u) << 16; return v.f;
}

// async 16B global->LDS (wave-uniform LDS base + lane*16)
__device__ __forceinline__ void async16(const unsigned short* g, unsigned short* l) {
  __builtin_amdgcn_global_load_lds(
      (const __attribute__((address_space(1))) unsigned int*)g,
      (__attribute__((address_space(3))) unsigned int*)l, 16, 0, 0);
}

// ---------------- alpha/beta epilogue constants + zero MEANS + zero page ---
__global__ void k_alpha_beta(const float* __restrict__ oft_b,
                             const float* __restrict__ g1, const float* __restrict__ b1,
                             const float* __restrict__ m1, const float* __restrict__ v1,
                             const float* __restrict__ g2, const float* __restrict__ b2,
                             const float* __restrict__ m2, const float* __restrict__ v2,
                             float* __restrict__ ALPHA, float* __restrict__ BETA,
                             float* __restrict__ MEANS, unsigned short* __restrict__ ZPAGE) {
  int g = blockIdx.x, c = threadIdx.x;
  float al, be;
  if (g < 5) { al = 1.f; be = oft_b[g * 256 + c]; MEANS[g * 256 + c] = 0.f; }
  else {
    const float* gg = (g == 5) ? g1 : g2;
    const float* bb = (g == 5) ? b1 : b2;
    const float* mm = (g == 5) ? m1 : m2;
    const float* vv = (g == 5) ? v1 : v2;
    al = gg[c] / sqrtf(vv[c] + 1e-5f);
    be = bb[c] - mm[c] * al;
  }
  ALPHA[g * 256 + c] = al; BETA[g * 256 + c] = be;
  if (g == 0) ZPAGE[c] = 0;
}

// ---------------- oft weights -> tiled B: [sc][cb2][s72][kc4][row128][j8] ---
__global__ void k_wpermT(const float* __restrict__ w, unsigned short* __restrict__ wp) {
  int idx = blockIdx.x * 256 + threadIdx.x;  // < 5*589824
  int sc = idx / 589824;
  int r  = idx % 589824;
  int j   = r & 7;
  int row = (r >> 3) & 127;
  int kc  = (r >> 10) & 3;
  int cs  = r >> 12;            // cb*72 + s
  int cb  = cs / 72, s = cs % 72;
  int oc = cb * 128 + row;
  int k  = s * 32 + kc * 8 + j; // k' = z*256 + c
  int z = k >> 8, c = k & 255;
  wp[idx] = f2bf(w[((size_t)sc * 256 + oc) * 2304 + c * 9 + z]);
}

// ---------------- conv1 weights -> tiled [cb2][r9][s40][kc4][row128][j8], *satt
__global__ void k_wperm1T(const float* __restrict__ w, const float* __restrict__ satt,
                          unsigned short* __restrict__ wp) {
  int idx = blockIdx.x * 256 + threadIdx.x;  // < 2*9*40*4096 = 2949120
  int j   = idx & 7;
  int row = (idx >> 3) & 127;
  int kc  = (idx >> 10) & 3;
  int rest = idx >> 12;          // (cb*9 + r)*40 + s
  int s = rest % 40; rest /= 40;
  int r = rest % 9;  int cb = rest / 9;
  int oc = cb * 128 + row;
  int ic = s * 32 + kc * 8 + j;  // < 1280
  wp[idx] = f2bf(w[(size_t)oc * 11520 + ic * 9 + r] * satt[ic]);
}

// ---------------- conv2 weights -> tiled [cb2][r9][s8][kc4][row128][j8] ----
__global__ void k_wperm2T(const float* __restrict__ w, unsigned short* __restrict__ wp) {
  int idx = blockIdx.x * 256 + threadIdx.x;  // < 2*9*8*4096 = 589824
  int j   = idx & 7;
  int row = (idx >> 3) & 127;
  int kc  = (idx >> 10) & 3;
  int rest = idx >> 12;          // (cb*9 + r)*8 + s
  int s = rest % 8; rest /= 8;
  int r = rest % 9; int cb = rest / 9;
  int oc = cb * 128 + row;
  int ic = s * 32 + kc * 8 + j;  // < 256
  wp[idx] = f2bf(w[(size_t)oc * 2304 + ic * 9 + r]);
}

// ---------------- bbox projection (scale-independent) ----------------------
__global__ void k_bbox(const float* __restrict__ calib, float* __restrict__ bbox) {
  int idx = blockIdx.x * 256 + threadIdx.x;
  if (idx >= ZC * NBOX) return;
  int z = idx / NBOX, n = idx % NBOX;
  int d = n / 124, wj = n % 124;
  float P[12];
#pragma unroll
  for (int i = 0; i < 12; ++i) P[i] = calib[i];
  auto proj = [&](int k, int i, int j, float& nx, float& ny) {
    float X = 0.64f * (float)i;
    float Y = 39.68f - 0.64f * (float)j;
    float Z = 2.76f - 0.64f * (float)k;
    float hx = P[0] * X + P[1] * Y + P[2]  * Z + P[3];
    float hy = P[4] * X + P[5] * Y + P[6]  * Z + P[7];
    float hz = P[8] * X + P[9] * Y + P[10] * Z + P[11];
    float px = hx / hz, py = hy / hz;
    nx = 2.f * px / 1280.f - 1.f; nx = fminf(fmaxf(nx, -1.f), 1.f);
    ny = 2.f * py / 384.f  - 1.f; ny = fminf(fmaxf(ny, -1.f), 1.f);
  };
  float ax, ay, bx, by, cx, cy, dx, dy;
  proj(z,     d,     wj,     ax, ay);
  proj(z,     d + 1, wj,     bx, by);
  proj(z + 1, d + 1, wj + 1, cx, cy);
  proj(z + 1, d,     wj + 1, dx, dy);
  float4v o;
  o[0] = fminf(ax, bx); o[1] = fminf(ay, by);
  o[2] = fmaxf(cx, dx); o[3] = fmaxf(cy, dy);
  *(float4v*)(bbox + (size_t)idx * 4) = o;
}

// ---------------- feats [256][S] f32 -> II [S][256] f32 (LDS transpose) ----
__global__ void k_transpose(const float* __restrict__ src, float* __restrict__ dst, int S) {
  __shared__ float tile[64][65];
  int t = threadIdx.x;
  int wave = t >> 6, lane = t & 63;
  int s0 = blockIdx.x * 64, c0 = blockIdx.y * 64;
#pragma unroll
  for (int i = 0; i < 16; ++i) {
    int c_l = wave * 16 + i;
    if (s0 + lane < S) tile[c_l][lane] = src[(size_t)(c0 + c_l) * S + s0 + lane];
  }
  __syncthreads();
#pragma unroll
  for (int i = 0; i < 16; ++i) {
    int s_l = wave * 16 + i;
    if (s0 + s_l < S) dst[(size_t)(s0 + s_l) * 256 + c0 + lane] = tile[lane][s_l];
  }
}

// ---------------- cumsum over w: ii [h][w][c], coalesced -------------------
__global__ void k_cumw(float* __restrict__ ii, int Wf) {
  int c = threadIdx.x, h = blockIdx.x;
  float* p = ii + (size_t)h * Wf * 256 + c;
  float acc = 0.f;
  for (int w = 0; w < Wf; ++w) { acc += p[(size_t)w * 256]; p[(size_t)w * 256] = acc; }
}

// ---------------- cumsum over h: ii [h][w][c], coalesced -------------------
__global__ void k_cumh(float* __restrict__ ii, int Hf, int Wf) {
  int c = threadIdx.x, w = blockIdx.x;
  float* p = ii + (size_t)w * 256 + c;
  size_t stride = (size_t)Wf * 256;
  float acc = 0.f;
  for (int h = 0; h < Hf; ++h) { acc += p[h * stride]; p[h * stride] = acc; }
}

// ---------------- box sampler: wave = one n, lane = 4 channels -------------
// writes VOX in GEMM tile-ready layout [nb][s][kc][row][8]
__global__ void k_sample(const float* __restrict__ ii, const float* __restrict__ bbox,
                         unsigned short* __restrict__ voxT, int Hf, int Wf, float areaScale) {
  int wave = threadIdx.x >> 6, lane = threadIdx.x & 63;
  int n = blockIdx.x * 4 + wave;
  int c4 = lane * 4;
  const float* base = ii + c4;
  int nb = n >> 7, row = n & 127;
  unsigned short* vb = voxT + (size_t)nb * NBSTRIDE + (size_t)row * 8
                     + (lane >> 3) * 4096 + ((lane >> 1) & 3) * 1024 + (lane & 1) * 4;
  for (int z = 0; z < ZC; ++z) {
    float4v bb = *(const float4v*)(bbox + ((size_t)z * NBOX + n) * 4);
    float x0 = bb[0], y0 = bb[1], x1 = bb[2], y1 = bb[3];
    float rawA = (x1 - x0) * (y1 - y0) * areaScale;
    ushort4v o;
    if (rawA > 0.f) {
      float inv = 1.f / (rawA + 1e-6f);
      float4v acc = {0.f, 0.f, 0.f, 0.f};
#pragma unroll
      for (int pt = 0; pt < 4; ++pt) {
        float gx = (pt == 0 || pt == 3) ? x0 : x1;
        float gy = (pt == 0 || pt == 2) ? y0 : y1;
        float sign = (pt < 2) ? 1.f : -1.f;
        float u = (gx + 1.f) * ((float)Wf * 0.5f) - 0.5f;
        float v = (gy + 1.f) * ((float)Hf * 0.5f) - 0.5f;
        float uf = floorf(u), vf = floorf(v);
        float wx = u - uf, wy = v - vf;
        int xi = (int)uf, yi = (int)vf;
        bool okx0 = (xi >= 0) && (xi < Wf);
        bool okx1 = (xi + 1 >= 0) && (xi + 1 < Wf);
        bool oky0 = (yi >= 0) && (yi < Hf);
        bool oky1 = (yi + 1 >= 0) && (yi + 1 < Hf);
        float w00 = sign * (1.f - wx) * (1.f - wy);
        float w01 = sign * wx * (1.f - wy);
        float w10 = sign * (1.f - wx) * wy;
        float w11 = sign * wx * wy;
        if (okx0 && oky0) acc += (*(const float4v*)(base + ((size_t)yi * Wf + xi) * 256)) * w00;
        if (okx1 && oky0) acc += (*(const float4v*)(base + ((size_t)yi * Wf + xi + 1) * 256)) * w01;
        if (okx0 && oky1) acc += (*(const float4v*)(base + ((size_t)(yi + 1) * Wf + xi) * 256)) * w10;
        if (okx1 && oky1) acc += (*(const float4v*)(base + ((size_t)(yi + 1) * Wf + xi + 1) * 256)) * w11;
      }
#pragma unroll
      for (int j = 0; j < 4; ++j) o[j] = f2bf(acc[j] * inv);
    } else {
      o[0] = 0; o[1] = 0; o[2] = 0; o[3] = 0;
    }
    *(ushort4v*)(vb + z * 32768) = o;
  }
}

// ---------------- OFT GEMM, split-K=3: raw f32 partials --------------------
// A = VOXT [nb][72][4096], B = WPERMT [cb][72][4096]
// part[ks][n][256] f32; grid (105, 2, 3)
__global__ __launch_bounds__(256) void k_gemmT(
    const unsigned short* __restrict__ AT, const unsigned short* __restrict__ BT,
    float* __restrict__ part) {
  __shared__ unsigned short lsA[4096];
  __shared__ unsigned short lsB[4096];
  int t = threadIdx.x;
  int lane = t & 63, wave = t >> 6;
  int l15 = lane & 15, quad = lane >> 4;
  int nb = blockIdx.x, cb = blockIdx.y, ks = blockIdx.z;
  int wrow = (wave >> 1) * 64, wcol = (wave & 1) * 64;

  const unsigned short* ga = AT + (size_t)nb * NBSTRIDE + (size_t)ks * 24 * TILEK + t * 8;
  const unsigned short* gb = BT + (size_t)cb * NBSTRIDE + (size_t)ks * 24 * TILEK + t * 8;
  unsigned short* ldA = lsA + t * 8;
  unsigned short* ldB = lsB + t * 8;

  float4v acc[4][4];
#pragma unroll
  for (int mi = 0; mi < 4; ++mi)
#pragma unroll
    for (int ni = 0; ni < 4; ++ni) acc[mi][ni] = (float4v){0.f, 0.f, 0.f, 0.f};

  for (int s = 0; s < 24; ++s) {
    async16(ga, ldA);
    async16(ga + 2048, ldA + 2048);
    async16(gb, ldB);
    async16(gb + 2048, ldB + 2048);
    ga += TILEK; gb += TILEK;
    __syncthreads();
    short8 af[4], bf[4];
    const short8* pA = (const short8*)lsA;
    const short8* pB = (const short8*)lsB;
#pragma unroll
    for (int mi = 0; mi < 4; ++mi) af[mi] = pA[quad * 128 + wrow + mi * 16 + l15];
#pragma unroll
    for (int ni = 0; ni < 4; ++ni) bf[ni] = pB[quad * 128 + wcol + ni * 16 + l15];
#pragma unroll
    for (int mi = 0; mi < 4; ++mi)
#pragma unroll
      for (int ni = 0; ni < 4; ++ni)
        acc[mi][ni] = __builtin_amdgcn_mfma_f32_16x16x32_bf16(af[mi], bf[ni], acc[mi][ni], 0, 0, 0);
    __syncthreads();
  }

#pragma unroll
  for (int mi = 0; mi < 4; ++mi) {
    int nb0 = nb * 128 + wrow + mi * 16 + quad * 4;
#pragma unroll
    for (int j = 0; j < 4; ++j) {
      int nn = nb0 + j;
      if (nn < NBOX) {
#pragma unroll
        for (int ni = 0; ni < 4; ++ni) {
          int oc = cb * 128 + wcol + ni * 16 + l15;
          part[((size_t)ks * NBOX + nn) * 256 + oc] = acc[mi][ni][j];
        }
      }
    }
  }
}

// reduce OFT partials -> XBUF [n][1280] @ choff (bias + relu, alpha=1)
__global__ void k_redoft(const float* __restrict__ part, const float* __restrict__ beta,
                         unsigned short* __restrict__ xbuf, int choff) {
  int n = blockIdx.x, oc = threadIdx.x;
  float v = part[(size_t)n * 256 + oc]
          + part[((size_t)NBOX + n) * 256 + oc]
          + part[((size_t)2 * NBOX + n) * 256 + oc];
  v += beta[oc];
  v = v > 0.f ? v : 0.f;
  xbuf[(size_t)n * 1280 + choff + oc] = f2bf(v);
}

// ---------------- conv GEMM, split by tap r: raw f32 partials --------------
// MODE 1: conv1 s2 gather from XBUF [sp][1280], B = WC1T [cb][9][40][4096]
// MODE 2: conv2 s1 gather from Y1 [sp][256],  B = WC2T [cb][9][8][4096]
// part[r][p][256]; grid (27, 2, 9)
template <int MODE>
__global__ __launch_bounds__(256) void k_gemmS(
    const unsigned short* __restrict__ A, const unsigned short* __restrict__ BT,
    float* __restrict__ part, const unsigned short* __restrict__ zpage) {
  constexpr int KIC   = (MODE == 1) ? 1280 : 256;
  constexpr int STEPS = KIC / 32;
  __shared__ unsigned short lsA[4096];
  __shared__ unsigned short lsB[4096];
  int t = threadIdx.x;
  int lane = t & 63, wave = t >> 6;
  int l15 = lane & 15, quad = lane >> 4;
  int n0 = blockIdx.x * 128, oc0 = blockIdx.y * 128;
  int r = blockIdx.z;
  int wrow = (wave >> 1) * 64, wcol = (wave & 1) * 64;
  int srow = t & 127, skc = t >> 7;

  int p = n0 + srow;
  int oy = p / 54, ox = p - oy * 54;
  int ky = r / 3, kx = r - ky * 3;
  bool valid; int sp;
  if (MODE == 1) {
    int ih = 2 * oy + ky - 1, iw = 2 * ox + kx - 1;
    valid = (p < NPIX) && ((unsigned)ih < 124u) && ((unsigned)iw < 108u);
    sp = iw * 124 + ih;
  } else {
    int ih = oy + ky - 1, iw = ox + kx - 1;
    valid = (p < NPIX) && ((unsigned)ih < 62u) && ((unsigned)iw < 54u);
    sp = ih * 54 + iw;
  }
  const unsigned short* ga = valid ? (A + (size_t)sp * KIC + skc * 8) : zpage;
  int astep = valid ? 32 : 0;
  const unsigned short* gb = BT + ((size_t)(blockIdx.y * 9 + r) * STEPS) * TILEK + t * 8;
  unsigned short* ldA = lsA + t * 8;
  unsigned short* ldB = lsB + t * 8;

  float4v acc[4][4];
#pragma unroll
  for (int mi = 0; mi < 4; ++mi)
#pragma unroll
    for (int ni = 0; ni < 4; ++ni) acc[mi][ni] = (float4v){0.f, 0.f, 0.f, 0.f};

  for (int s = 0; s < STEPS; ++s) {
    async16(ga, ldA);
    async16(ga + 16, ldA + 2048);
    async16(gb, ldB);
    async16(gb + 2048, ldB + 2048);
    ga += astep; gb += TILEK;
    __syncthreads();
    short8 af[4], bf[4];
    const short8* pA = (const short8*)lsA;
    const short8* pB = (const short8*)lsB;
#pragma unroll
    for (int mi = 0; mi < 4; ++mi) af[mi] = pA[quad * 128 + wrow + mi * 16 + l15];
#pragma unroll
    for (int ni = 0; ni < 4; ++ni) bf[ni] = pB[quad * 128 + wcol + ni * 16 + l15];
#pragma unroll
    for (int mi = 0; mi < 4; ++mi)
#pragma unroll
      for (int ni = 0; ni < 4; ++ni)
        acc[mi][ni] = __builtin_amdgcn_mfma_f32_16x16x32_bf16(af[mi], bf[ni], acc[mi][ni], 0, 0, 0);
    __syncthreads();
  }

#pragma unroll
  for (int mi = 0; mi < 4; ++mi) {
    int nb0 = n0 + wrow + mi * 16 + quad * 4;
#pragma unroll
    for (int j = 0; j < 4; ++j) {
      int nn = nb0 + j;
      if (nn < NPIX) {
#pragma unroll
        for (int ni = 0; ni < 4; ++ni) {
          int oc = oc0 + wcol + ni * 16 + l15;
          part[((size_t)r * NPIX + nn) * 256 + oc] = acc[mi][ni][j];
        }
      }
    }
  }
}

// reduce conv partials (9 taps) with alpha/beta + relu
template <bool F32OUT>
__global__ void k_redconv(const float* __restrict__ part, const float* __restrict__ alpha,
                          const float* __restrict__ beta, void* __restrict__ outv) {
  int p = blockIdx.x, oc = threadIdx.x;
  float v = 0.f;
#pragma unroll
  for (int r = 0; r < 9; ++r) v += part[((size_t)r * NPIX + p) * 256 + oc];
  v = v * alpha[oc] + beta[oc];
  v = v > 0.f ? v : 0.f;
  if (F32OUT) ((float*)outv)[(size_t)oc * NPIX + p] = v;
  else ((unsigned short*)outv)[(size_t)p * 256 + oc] = f2bf(v);
}

// ---------------- channel means over XBUF [n][1280] ------------------------
__global__ void k_means2(const unsigned short* __restrict__ x, float* __restrict__ means) {
  int tid = threadIdx.x;
  int r0 = blockIdx.x * 64;
  float part[5] = {0.f, 0.f, 0.f, 0.f, 0.f};
  for (int i = 0; i < 64; ++i) {
    int row = r0 + i;
    if (row < NBOX) {
      const unsigned short* rp = x + (size_t)row * 1280;
#pragma unroll
      for (int g = 0; g < 5; ++g) part[g] += bf2f(rp[g * 256 + tid]);
    }
  }
#pragma unroll
  for (int g = 0; g < 5; ++g) atomicAdd(&means[g * 256 + tid], part[g]);
}

__global__ void k_att(const float* __restrict__ means, const float* __restrict__ aw,
                      const float* __restrict__ ab, float* __restrict__ satt) {
  int sc = blockIdx.x, c = threadIdx.x;
  __shared__ float m[256];
  m[c] = means[sc * 256 + c] * (1.f / (float)NBOX);
  __syncthreads();
  float acc = ab[c];
  for (int j = 0; j < 256; ++j) acc += m[j] * aw[c * 256 + j];
  satt[sc * 256 + c] = 1.f / (1.f + expf(-acc));
}

extern "C" void kernel_launch(void* const* d_in, const int* in_sizes, int n_in,
                              void* d_out, int out_size, void* d_ws, size_t ws_size,
                              hipStream_t stream) {
  const float* feats[5];
  for (int i = 0; i < 5; ++i) feats[i] = (const float*)d_in[i];
  const float* calib   = (const float*)d_in[5];
  const float* oft_w   = (const float*)d_in[6];
  const float* oft_b   = (const float*)d_in[7];
  const float* att_w   = (const float*)d_in[8];
  const float* att_b   = (const float*)d_in[9];
  const float* conv1_w = (const float*)d_in[10];
  const float* bn1g = (const float*)d_in[11];
  const float* bn1b = (const float*)d_in[12];
  const float* bn1m = (const float*)d_in[13];
  const float* bn1v = (const float*)d_in[14];
  const float* conv2_w = (const float*)d_in[15];
  const float* bn2g = (const float*)d_in[16];
  const float* bn2b = (const float*)d_in[17];
  const float* bn2m = (const float*)d_in[18];
  const float* bn2v = (const float*)d_in[19];

  char* ws = (char*)d_ws;
  size_t off = 0;
  auto alloc = [&](size_t bytes) -> void* {
    void* p = ws + off; off += (bytes + 255) & ~(size_t)255; return p;
  };
  float*          BBOX   = (float*)alloc((size_t)ZC * NBOX * 4 * 4);
  unsigned short* WPERMT = (unsigned short*)alloc((size_t)5 * 589824 * 2);
  unsigned short* WC1T   = (unsigned short*)alloc((size_t)2949120 * 2);
  unsigned short* WC2T   = (unsigned short*)alloc((size_t)589824 * 2);
  float*          II     = (float*)alloc((size_t)10475520 * 4);
  unsigned short* VOXT   = (unsigned short*)alloc((size_t)NBLK0 * NBSTRIDE * 2);
  unsigned short* XBUF   = (unsigned short*)alloc((size_t)NBOX * 1280 * 2);
  unsigned short* Y1     = (unsigned short*)alloc((size_t)NPIX * 256 * 2);
  float*          PART   = (float*)alloc((size_t)OFT_SPLIT * NBOX * 256 * 4); // 41 MB, also fits 9*NPIX*256
  float*          MEANS  = (float*)alloc(1280 * 4);
  float*          SATT   = (float*)alloc(1280 * 4);
  float*          ALPHA  = (float*)alloc(7 * 256 * 4);
  float*          BETA   = (float*)alloc(7 * 256 * 4);
  unsigned short* ZPAGE  = (unsigned short*)alloc(256 * 2);
  (void)ws_size; (void)in_sizes; (void)n_in; (void)out_size;

  static const int HFs[5] = {96, 48, 24, 12, 6};
  static const int WFs[5] = {320, 160, 80, 40, 20};
  static const size_t IIoff[5] = {0, 7864320, 9830400, 10321920, 10444800};

  k_alpha_beta<<<7, 256, 0, stream>>>(oft_b, bn1g, bn1b, bn1m, bn1v,
                                      bn2g, bn2b, bn2m, bn2v, ALPHA, BETA, MEANS, ZPAGE);
  k_wpermT<<<11520, 256, 0, stream>>>(oft_w, WPERMT);
  k_wperm2T<<<2304, 256, 0, stream>>>(conv2_w, WC2T);
  k_bbox<<<(ZC * NBOX + 255) / 256, 256, 0, stream>>>(calib, BBOX);

  for (int s = 0; s < 5; ++s) {
    int S = HFs[s] * WFs[s];
    k_transpose<<<dim3((S + 63) / 64, 4), 256, 0, stream>>>(feats[s], II + IIoff[s], S);
    k_cumw<<<HFs[s], 256, 0, stream>>>(II + IIoff[s], WFs[s]);
    k_cumh<<<WFs[s], 256, 0, stream>>>(II + IIoff[s], HFs[s], WFs[s]);
  }
  for (int s = 0; s < 5; ++s) {
    k_sample<<<NBOX / 4, 256, 0, stream>>>(II + IIoff[s], BBOX, VOXT, HFs[s], WFs[s],
                                           (float)(HFs[s] * WFs[s]) * 0.25f);
    k_gemmT<<<dim3(NBLK0, 2, OFT_SPLIT), 256, 0, stream>>>(
        VOXT, WPERMT + (size_t)s * 589824, PART);
    k_redoft<<<NBOX, 256, 0, stream>>>(PART, BETA + s * 256, XBUF, s * 256);
  }
  k_means2<<<(NBOX + 63) / 64, 256, 0, stream>>>(XBUF, MEANS);
  k_att<<<5, 256, 0, stream>>>(MEANS, att_w, att_b, SATT);
  k_wperm1T<<<11520, 256, 0, stream>>>(conv1_w, SATT, WC1T);

  k_gemmS<1><<<dim3(NBLKC, 2, 9), 256, 0, stream>>>(XBUF, WC1T, PART, ZPAGE);
  k_redconv<false><<<NPIX, 256, 0, stream>>>(PART, ALPHA + 5 * 256, BETA + 5 * 256, Y1);

  k_gemmS<2><<<dim3(NBLKC, 2, 9), 256, 0, stream>>>(Y1, WC2T, PART, ZPAGE);
  k_redconv<true><<<NPIX, 256, 0, stream>>>(PART, ALPHA + 6 * 256, BETA + 6 * 256, d_out);
}

// Round 7
// 1041.599 us; speedup vs baseline: 2.4699x; 1.1180x over previous
//
#include <hip/hip_runtime.h>

typedef __attribute__((ext_vector_type(8))) short short8;
typedef __attribute__((ext_vector_type(4))) float float4v;
typedef __attribute__((ext_vector_type(4))) unsigned short ushort4v;

#define NBOX 13392   // 108*124 bev cells (n = d*124 + wj)
#define ZC 9
#define KOFT 2304    // 9*256, k = z*256+c
#define NPIX 3348    // 62*54
#define NBLK0 105    // ceil(13392/128)
#define NBLKC 27     // ceil(3348/128)
#define TILEK 4096   // shorts per 8KB step-tile [kc4][row128][8]
#define NBSTRIDE 294912  // 72 steps * 4096 shorts per row-block / col-block
#define OFT_SPLIT 4      // 18 steps per split chunk

__device__ __forceinline__ unsigned short f2bf(float f) {
  union { float f; unsigned int i; } v; v.f = f;
  unsigned int r = v.i + 0x7FFFu + ((v.i >> 16) & 1u);
  return (unsigned short)(r >> 16);
}
__device__ __forceinline__ float bf2f(unsigned short u) {
  union { unsigned int i; float f; } v; v.i = ((unsigned int)u) << 16; return v.f;
}

// async 16B global->LDS (wave-uniform LDS base + lane*16)
__device__ __forceinline__ void async16(const unsigned short* g, unsigned short* l) {
  __builtin_amdgcn_global_load_lds(
      (const __attribute__((address_space(1))) unsigned int*)g,
      (__attribute__((address_space(3))) unsigned int*)l, 16, 0, 0);
}

// ---------------- alpha/beta epilogue constants + zero MEANS + zero page ---
__global__ void k_alpha_beta(const float* __restrict__ oft_b,
                             const float* __restrict__ g1, const float* __restrict__ b1,
                             const float* __restrict__ m1, const float* __restrict__ v1,
                             const float* __restrict__ g2, const float* __restrict__ b2,
                             const float* __restrict__ m2, const float* __restrict__ v2,
                             float* __restrict__ ALPHA, float* __restrict__ BETA,
                             float* __restrict__ MEANS, unsigned short* __restrict__ ZPAGE) {
  int g = blockIdx.x, c = threadIdx.x;
  float al, be;
  if (g < 5) { al = 1.f; be = oft_b[g * 256 + c]; MEANS[g * 256 + c] = 0.f; }
  else {
    const float* gg = (g == 5) ? g1 : g2;
    const float* bb = (g == 5) ? b1 : b2;
    const float* mm = (g == 5) ? m1 : m2;
    const float* vv = (g == 5) ? v1 : v2;
    al = gg[c] / sqrtf(vv[c] + 1e-5f);
    be = bb[c] - mm[c] * al;
  }
  ALPHA[g * 256 + c] = al; BETA[g * 256 + c] = be;
  if (g == 0) ZPAGE[c] = 0;
}

// ---------------- oft weights -> tiled B: [sc][cb2][s72][kc4][row128][j8] ---
__global__ void k_wpermT(const float* __restrict__ w, unsigned short* __restrict__ wp) {
  int idx = blockIdx.x * 256 + threadIdx.x;  // < 5*589824
  int sc = idx / 589824;
  int r  = idx % 589824;
  int j   = r & 7;
  int row = (r >> 3) & 127;
  int kc  = (r >> 10) & 3;
  int cs  = r >> 12;            // cb*72 + s
  int cb  = cs / 72, s = cs % 72;
  int oc = cb * 128 + row;
  int k  = s * 32 + kc * 8 + j; // k' = z*256 + c
  int z = k >> 8, c = k & 255;
  wp[idx] = f2bf(w[((size_t)sc * 256 + oc) * 2304 + c * 9 + z]);
}

// ---------------- conv1 weights -> tiled [cb2][r9][s40][kc4][row128][j8], *satt
__global__ void k_wperm1T(const float* __restrict__ w, const float* __restrict__ satt,
                          unsigned short* __restrict__ wp) {
  int idx = blockIdx.x * 256 + threadIdx.x;  // < 2*9*40*4096 = 2949120
  int j   = idx & 7;
  int row = (idx >> 3) & 127;
  int kc  = (idx >> 10) & 3;
  int rest = idx >> 12;          // (cb*9 + r)*40 + s
  int s = rest % 40; rest /= 40;
  int r = rest % 9;  int cb = rest / 9;
  int oc = cb * 128 + row;
  int ic = s * 32 + kc * 8 + j;  // < 1280
  wp[idx] = f2bf(w[(size_t)oc * 11520 + ic * 9 + r] * satt[ic]);
}

// ---------------- conv2 weights -> tiled [cb2][r9][s8][kc4][row128][j8] ----
__global__ void k_wperm2T(const float* __restrict__ w, unsigned short* __restrict__ wp) {
  int idx = blockIdx.x * 256 + threadIdx.x;  // < 2*9*8*4096 = 589824
  int j   = idx & 7;
  int row = (idx >> 3) & 127;
  int kc  = (idx >> 10) & 3;
  int rest = idx >> 12;          // (cb*9 + r)*8 + s
  int s = rest % 8; rest /= 8;
  int r = rest % 9; int cb = rest / 9;
  int oc = cb * 128 + row;
  int ic = s * 32 + kc * 8 + j;  // < 256
  wp[idx] = f2bf(w[(size_t)oc * 2304 + ic * 9 + r]);
}

// ---------------- bbox projection (scale-independent) ----------------------
__global__ void k_bbox(const float* __restrict__ calib, float* __restrict__ bbox) {
  int idx = blockIdx.x * 256 + threadIdx.x;
  if (idx >= ZC * NBOX) return;
  int z = idx / NBOX, n = idx % NBOX;
  int d = n / 124, wj = n % 124;
  float P[12];
#pragma unroll
  for (int i = 0; i < 12; ++i) P[i] = calib[i];
  auto proj = [&](int k, int i, int j, float& nx, float& ny) {
    float X = 0.64f * (float)i;
    float Y = 39.68f - 0.64f * (float)j;
    float Z = 2.76f - 0.64f * (float)k;
    float hx = P[0] * X + P[1] * Y + P[2]  * Z + P[3];
    float hy = P[4] * X + P[5] * Y + P[6]  * Z + P[7];
    float hz = P[8] * X + P[9] * Y + P[10] * Z + P[11];
    float px = hx / hz, py = hy / hz;
    nx = 2.f * px / 1280.f - 1.f; nx = fminf(fmaxf(nx, -1.f), 1.f);
    ny = 2.f * py / 384.f  - 1.f; ny = fminf(fmaxf(ny, -1.f), 1.f);
  };
  float ax, ay, bx, by, cx, cy, dx, dy;
  proj(z,     d,     wj,     ax, ay);
  proj(z,     d + 1, wj,     bx, by);
  proj(z + 1, d + 1, wj + 1, cx, cy);
  proj(z + 1, d,     wj + 1, dx, dy);
  float4v o;
  o[0] = fminf(ax, bx); o[1] = fminf(ay, by);
  o[2] = fmaxf(cx, dx); o[3] = fmaxf(cy, dy);
  *(float4v*)(bbox + (size_t)idx * 4) = o;
}

// ---------------- merged feats transpose: [256][S] f32 -> II [S][256] ------
// grid (640, 4): chunk starts per scale {0,480,600,630,638}
__global__ void k_transpose_all(const float* __restrict__ f0, const float* __restrict__ f1,
                                const float* __restrict__ f2, const float* __restrict__ f3,
                                const float* __restrict__ f4, float* __restrict__ II) {
  int b = blockIdx.x;
  int sc, cx;
  if (b < 480)      { sc = 0; cx = b; }
  else if (b < 600) { sc = 1; cx = b - 480; }
  else if (b < 630) { sc = 2; cx = b - 600; }
  else if (b < 638) { sc = 3; cx = b - 630; }
  else              { sc = 4; cx = b - 638; }
  const int Ss[5] = {30720, 7680, 1920, 480, 120};
  const size_t IIof[5] = {0, 7864320, 9830400, 10321920, 10444800};
  const float* srcs[5] = {f0, f1, f2, f3, f4};
  int S = Ss[sc];
  const float* src = srcs[sc];
  float* dst = II + IIof[sc];
  __shared__ float tile[64][65];
  int t = threadIdx.x;
  int wave = t >> 6, lane = t & 63;
  int s0 = cx * 64, c0 = blockIdx.y * 64;
#pragma unroll
  for (int i = 0; i < 16; ++i) {
    int c_l = wave * 16 + i;
    if (s0 + lane < S) tile[c_l][lane] = src[(size_t)(c0 + c_l) * S + s0 + lane];
  }
  __syncthreads();
#pragma unroll
  for (int i = 0; i < 16; ++i) {
    int s_l = wave * 16 + i;
    if (s0 + s_l < S) dst[(size_t)(s0 + s_l) * 256 + c0 + lane] = tile[lane][s_l];
  }
}

// ---------------- merged cumsum over w: grid 186 ---------------------------
__global__ void k_cumw_all(float* __restrict__ II) {
  int b = blockIdx.x;
  int sc, h;
  if (b < 96)       { sc = 0; h = b; }
  else if (b < 144) { sc = 1; h = b - 96; }
  else if (b < 168) { sc = 2; h = b - 144; }
  else if (b < 180) { sc = 3; h = b - 168; }
  else              { sc = 4; h = b - 180; }
  const int Wfs[5] = {320, 160, 80, 40, 20};
  const size_t IIof[5] = {0, 7864320, 9830400, 10321920, 10444800};
  int Wf = Wfs[sc];
  float* p = II + IIof[sc] + (size_t)h * Wf * 256 + threadIdx.x;
  float acc = 0.f;
#pragma unroll 4
  for (int w = 0; w < Wf; ++w) { acc += p[(size_t)w * 256]; p[(size_t)w * 256] = acc; }
}

// ---------------- merged cumsum over h: grid 620 ---------------------------
__global__ void k_cumh_all(float* __restrict__ II) {
  int b = blockIdx.x;
  int sc, w;
  if (b < 320)      { sc = 0; w = b; }
  else if (b < 480) { sc = 1; w = b - 320; }
  else if (b < 560) { sc = 2; w = b - 480; }
  else if (b < 600) { sc = 3; w = b - 560; }
  else              { sc = 4; w = b - 600; }
  const int Wfs[5] = {320, 160, 80, 40, 20};
  const int Hfs[5] = {96, 48, 24, 12, 6};
  const size_t IIof[5] = {0, 7864320, 9830400, 10321920, 10444800};
  int Hf = Hfs[sc];
  size_t stride = (size_t)Wfs[sc] * 256;
  float* p = II + IIof[sc] + (size_t)w * 256 + threadIdx.x;
  float acc = 0.f;
#pragma unroll 4
  for (int h = 0; h < Hf; ++h) { acc += p[h * stride]; p[h * stride] = acc; }
}

// ---------------- box sampler: wave = one n, 3 z per wave ------------------
// grid (NBOX/4, 3); 4 independent per-point accumulators (short dep chains)
__global__ void k_sample(const float* __restrict__ ii, const float* __restrict__ bbox,
                         unsigned short* __restrict__ voxT, int Hf, int Wf, float areaScale) {
  int wave = threadIdx.x >> 6, lane = threadIdx.x & 63;
  int n = blockIdx.x * 4 + wave;
  int zg = blockIdx.y * 3;
  int c4 = lane * 4;
  const float* base = ii + c4;
  int nb = n >> 7, row = n & 127;
  unsigned short* vb = voxT + (size_t)nb * NBSTRIDE + (size_t)row * 8
                     + (lane >> 3) * 4096 + ((lane >> 1) & 3) * 1024 + (lane & 1) * 4;
#pragma unroll
  for (int dz = 0; dz < 3; ++dz) {
    int z = zg + dz;
    float4v bb = *(const float4v*)(bbox + ((size_t)z * NBOX + n) * 4);
    float x0 = bb[0], y0 = bb[1], x1 = bb[2], y1 = bb[3];
    float rawA = (x1 - x0) * (y1 - y0) * areaScale;
    ushort4v o;
    if (rawA > 0.f) {
      float inv = 1.f / (rawA + 1e-6f);
      float4v pa[4];
#pragma unroll
      for (int pt = 0; pt < 4; ++pt) {
        pa[pt] = (float4v){0.f, 0.f, 0.f, 0.f};
        float gx = (pt == 0 || pt == 3) ? x0 : x1;
        float gy = (pt == 0 || pt == 2) ? y0 : y1;
        float u = (gx + 1.f) * ((float)Wf * 0.5f) - 0.5f;
        float v = (gy + 1.f) * ((float)Hf * 0.5f) - 0.5f;
        float uf = floorf(u), vf = floorf(v);
        float wx = u - uf, wy = v - vf;
        int xi = (int)uf, yi = (int)vf;
        bool okx0 = (xi >= 0) && (xi < Wf);
        bool okx1 = (xi + 1 >= 0) && (xi + 1 < Wf);
        bool oky0 = (yi >= 0) && (yi < Hf);
        bool oky1 = (yi + 1 >= 0) && (yi + 1 < Hf);
        float w00 = (1.f - wx) * (1.f - wy);
        float w01 = wx * (1.f - wy);
        float w10 = (1.f - wx) * wy;
        float w11 = wx * wy;
        if (okx0 && oky0) pa[pt] += (*(const float4v*)(base + ((size_t)yi * Wf + xi) * 256)) * w00;
        if (okx1 && oky0) pa[pt] += (*(const float4v*)(base + ((size_t)yi * Wf + xi + 1) * 256)) * w01;
        if (okx0 && oky1) pa[pt] += (*(const float4v*)(base + ((size_t)(yi + 1) * Wf + xi) * 256)) * w10;
        if (okx1 && oky1) pa[pt] += (*(const float4v*)(base + ((size_t)(yi + 1) * Wf + xi + 1) * 256)) * w11;
      }
      float4v acc = (pa[0] + pa[1]) - (pa[2] + pa[3]);
#pragma unroll
      for (int j = 0; j < 4; ++j) o[j] = f2bf(acc[j] * inv);
    } else {
      o[0] = 0; o[1] = 0; o[2] = 0; o[3] = 0;
    }
    *(ushort4v*)(vb + z * 32768) = o;
  }
}

// ---------------- OFT GEMM, split-K=4: raw f32 partials --------------------
// A = VOXT [nb][72][4096], B = WPERMT [cb][72][4096]
// part[ks][n][256] f32; grid (105, 2, 4), 18 steps each
__global__ __launch_bounds__(256) void k_gemmT(
    const unsigned short* __restrict__ AT, const unsigned short* __restrict__ BT,
    float* __restrict__ part) {
  __shared__ unsigned short lsA[4096];
  __shared__ unsigned short lsB[4096];
  int t = threadIdx.x;
  int lane = t & 63, wave = t >> 6;
  int l15 = lane & 15, quad = lane >> 4;
  int nb = blockIdx.x, cb = blockIdx.y, ks = blockIdx.z;
  int wrow = (wave >> 1) * 64, wcol = (wave & 1) * 64;

  const unsigned short* ga = AT + (size_t)nb * NBSTRIDE + (size_t)ks * 18 * TILEK + t * 8;
  const unsigned short* gb = BT + (size_t)cb * NBSTRIDE + (size_t)ks * 18 * TILEK + t * 8;
  unsigned short* ldA = lsA + t * 8;
  unsigned short* ldB = lsB + t * 8;

  float4v acc[4][4];
#pragma unroll
  for (int mi = 0; mi < 4; ++mi)
#pragma unroll
    for (int ni = 0; ni < 4; ++ni) acc[mi][ni] = (float4v){0.f, 0.f, 0.f, 0.f};

  for (int s = 0; s < 18; ++s) {
    async16(ga, ldA);
    async16(ga + 2048, ldA + 2048);
    async16(gb, ldB);
    async16(gb + 2048, ldB + 2048);
    ga += TILEK; gb += TILEK;
    __syncthreads();
    short8 af[4], bf[4];
    const short8* pA = (const short8*)lsA;
    const short8* pB = (const short8*)lsB;
#pragma unroll
    for (int mi = 0; mi < 4; ++mi) af[mi] = pA[quad * 128 + wrow + mi * 16 + l15];
#pragma unroll
    for (int ni = 0; ni < 4; ++ni) bf[ni] = pB[quad * 128 + wcol + ni * 16 + l15];
#pragma unroll
    for (int mi = 0; mi < 4; ++mi)
#pragma unroll
      for (int ni = 0; ni < 4; ++ni)
        acc[mi][ni] = __builtin_amdgcn_mfma_f32_16x16x32_bf16(af[mi], bf[ni], acc[mi][ni], 0, 0, 0);
    __syncthreads();
  }

#pragma unroll
  for (int mi = 0; mi < 4; ++mi) {
    int nb0 = nb * 128 + wrow + mi * 16 + quad * 4;
#pragma unroll
    for (int j = 0; j < 4; ++j) {
      int nn = nb0 + j;
      if (nn < NBOX) {
#pragma unroll
        for (int ni = 0; ni < 4; ++ni) {
          int oc = cb * 128 + wcol + ni * 16 + l15;
          part[((size_t)ks * NBOX + nn) * 256 + oc] = acc[mi][ni][j];
        }
      }
    }
  }
}

// reduce OFT partials -> XBUF [n][1280] @ choff (bias + relu, alpha=1)
__global__ void k_redoft(const float* __restrict__ part, const float* __restrict__ beta,
                         unsigned short* __restrict__ xbuf, int choff) {
  int n = blockIdx.x, oc = threadIdx.x;
  float v = part[(size_t)n * 256 + oc]
          + part[((size_t)NBOX + n) * 256 + oc]
          + part[((size_t)2 * NBOX + n) * 256 + oc]
          + part[((size_t)3 * NBOX + n) * 256 + oc];
  v += beta[oc];
  v = v > 0.f ? v : 0.f;
  xbuf[(size_t)n * 1280 + choff + oc] = f2bf(v);
}

// ---------------- conv GEMM, split by tap r: raw f32 partials --------------
// MODE 1: conv1 s2 gather from XBUF [sp][1280], B = WC1T [cb][9][40][4096]
// MODE 2: conv2 s1 gather from Y1 [sp][256],  B = WC2T [cb][9][8][4096]
// part[r][p][256]; grid (27, 2, 9)
template <int MODE>
__global__ __launch_bounds__(256) void k_gemmS(
    const unsigned short* __restrict__ A, const unsigned short* __restrict__ BT,
    float* __restrict__ part, const unsigned short* __restrict__ zpage) {
  constexpr int KIC   = (MODE == 1) ? 1280 : 256;
  constexpr int STEPS = KIC / 32;
  __shared__ unsigned short lsA[4096];
  __shared__ unsigned short lsB[4096];
  int t = threadIdx.x;
  int lane = t & 63, wave = t >> 6;
  int l15 = lane & 15, quad = lane >> 4;
  int n0 = blockIdx.x * 128, oc0 = blockIdx.y * 128;
  int r = blockIdx.z;
  int wrow = (wave >> 1) * 64, wcol = (wave & 1) * 64;
  int srow = t & 127, skc = t >> 7;

  int p = n0 + srow;
  int oy = p / 54, ox = p - oy * 54;
  int ky = r / 3, kx = r - ky * 3;
  bool valid; int sp;
  if (MODE == 1) {
    int ih = 2 * oy + ky - 1, iw = 2 * ox + kx - 1;
    valid = (p < NPIX) && ((unsigned)ih < 124u) && ((unsigned)iw < 108u);
    sp = iw * 124 + ih;
  } else {
    int ih = oy + ky - 1, iw = ox + kx - 1;
    valid = (p < NPIX) && ((unsigned)ih < 62u) && ((unsigned)iw < 54u);
    sp = ih * 54 + iw;
  }
  const unsigned short* ga = valid ? (A + (size_t)sp * KIC + skc * 8) : zpage;
  int astep = valid ? 32 : 0;
  const unsigned short* gb = BT + ((size_t)(blockIdx.y * 9 + r) * STEPS) * TILEK + t * 8;
  unsigned short* ldA = lsA + t * 8;
  unsigned short* ldB = lsB + t * 8;

  float4v acc[4][4];
#pragma unroll
  for (int mi = 0; mi < 4; ++mi)
#pragma unroll
    for (int ni = 0; ni < 4; ++ni) acc[mi][ni] = (float4v){0.f, 0.f, 0.f, 0.f};

  for (int s = 0; s < STEPS; ++s) {
    async16(ga, ldA);
    async16(ga + 16, ldA + 2048);
    async16(gb, ldB);
    async16(gb + 2048, ldB + 2048);
    ga += astep; gb += TILEK;
    __syncthreads();
    short8 af[4], bf[4];
    const short8* pA = (const short8*)lsA;
    const short8* pB = (const short8*)lsB;
#pragma unroll
    for (int mi = 0; mi < 4; ++mi) af[mi] = pA[quad * 128 + wrow + mi * 16 + l15];
#pragma unroll
    for (int ni = 0; ni < 4; ++ni) bf[ni] = pB[quad * 128 + wcol + ni * 16 + l15];
#pragma unroll
    for (int mi = 0; mi < 4; ++mi)
#pragma unroll
      for (int ni = 0; ni < 4; ++ni)
        acc[mi][ni] = __builtin_amdgcn_mfma_f32_16x16x32_bf16(af[mi], bf[ni], acc[mi][ni], 0, 0, 0);
    __syncthreads();
  }

#pragma unroll
  for (int mi = 0; mi < 4; ++mi) {
    int nb0 = n0 + wrow + mi * 16 + quad * 4;
#pragma unroll
    for (int j = 0; j < 4; ++j) {
      int nn = nb0 + j;
      if (nn < NPIX) {
#pragma unroll
        for (int ni = 0; ni < 4; ++ni) {
          int oc = oc0 + wcol + ni * 16 + l15;
          part[((size_t)r * NPIX + nn) * 256 + oc] = acc[mi][ni][j];
        }
      }
    }
  }
}

// reduce conv partials (9 taps) with alpha/beta + relu
template <bool F32OUT>
__global__ void k_redconv(const float* __restrict__ part, const float* __restrict__ alpha,
                          const float* __restrict__ beta, void* __restrict__ outv) {
  int p = blockIdx.x, oc = threadIdx.x;
  float v = 0.f;
#pragma unroll
  for (int r = 0; r < 9; ++r) v += part[((size_t)r * NPIX + p) * 256 + oc];
  v = v * alpha[oc] + beta[oc];
  v = v > 0.f ? v : 0.f;
  if (F32OUT) ((float*)outv)[(size_t)oc * NPIX + p] = v;
  else ((unsigned short*)outv)[(size_t)p * 256 + oc] = f2bf(v);
}

// ---------------- channel means over XBUF [n][1280] ------------------------
__global__ void k_means2(const unsigned short* __restrict__ x, float* __restrict__ means) {
  int tid = threadIdx.x;
  int r0 = blockIdx.x * 64;
  float part[5] = {0.f, 0.f, 0.f, 0.f, 0.f};
  for (int i = 0; i < 64; ++i) {
    int row = r0 + i;
    if (row < NBOX) {
      const unsigned short* rp = x + (size_t)row * 1280;
#pragma unroll
      for (int g = 0; g < 5; ++g) part[g] += bf2f(rp[g * 256 + tid]);
    }
  }
#pragma unroll
  for (int g = 0; g < 5; ++g) atomicAdd(&means[g * 256 + tid], part[g]);
}

__global__ void k_att(const float* __restrict__ means, const float* __restrict__ aw,
                      const float* __restrict__ ab, float* __restrict__ satt) {
  int sc = blockIdx.x, c = threadIdx.x;
  __shared__ float m[256];
  m[c] = means[sc * 256 + c] * (1.f / (float)NBOX);
  __syncthreads();
  float acc = ab[c];
  for (int j = 0; j < 256; ++j) acc += m[j] * aw[c * 256 + j];
  satt[sc * 256 + c] = 1.f / (1.f + expf(-acc));
}

extern "C" void kernel_launch(void* const* d_in, const int* in_sizes, int n_in,
                              void* d_out, int out_size, void* d_ws, size_t ws_size,
                              hipStream_t stream) {
  const float* feats[5];
  for (int i = 0; i < 5; ++i) feats[i] = (const float*)d_in[i];
  const float* calib   = (const float*)d_in[5];
  const float* oft_w   = (const float*)d_in[6];
  const float* oft_b   = (const float*)d_in[7];
  const float* att_w   = (const float*)d_in[8];
  const float* att_b   = (const float*)d_in[9];
  const float* conv1_w = (const float*)d_in[10];
  const float* bn1g = (const float*)d_in[11];
  const float* bn1b = (const float*)d_in[12];
  const float* bn1m = (const float*)d_in[13];
  const float* bn1v = (const float*)d_in[14];
  const float* conv2_w = (const float*)d_in[15];
  const float* bn2g = (const float*)d_in[16];
  const float* bn2b = (const float*)d_in[17];
  const float* bn2m = (const float*)d_in[18];
  const float* bn2v = (const float*)d_in[19];

  char* ws = (char*)d_ws;
  size_t off = 0;
  auto alloc = [&](size_t bytes) -> void* {
    void* p = ws + off; off += (bytes + 255) & ~(size_t)255; return p;
  };
  float*          BBOX   = (float*)alloc((size_t)ZC * NBOX * 4 * 4);
  unsigned short* WPERMT = (unsigned short*)alloc((size_t)5 * 589824 * 2);
  unsigned short* WC1T   = (unsigned short*)alloc((size_t)2949120 * 2);
  unsigned short* WC2T   = (unsigned short*)alloc((size_t)589824 * 2);
  float*          II     = (float*)alloc((size_t)10475520 * 4);
  unsigned short* VOXT   = (unsigned short*)alloc((size_t)NBLK0 * NBSTRIDE * 2);
  unsigned short* XBUF   = (unsigned short*)alloc((size_t)NBOX * 1280 * 2);
  unsigned short* Y1     = (unsigned short*)alloc((size_t)NPIX * 256 * 2);
  float*          PART   = (float*)alloc((size_t)OFT_SPLIT * NBOX * 256 * 4); // 54.8 MB
  float*          MEANS  = (float*)alloc(1280 * 4);
  float*          SATT   = (float*)alloc(1280 * 4);
  float*          ALPHA  = (float*)alloc(7 * 256 * 4);
  float*          BETA   = (float*)alloc(7 * 256 * 4);
  unsigned short* ZPAGE  = (unsigned short*)alloc(256 * 2);
  (void)ws_size; (void)in_sizes; (void)n_in; (void)out_size;

  static const int HFs[5] = {96, 48, 24, 12, 6};
  static const int WFs[5] = {320, 160, 80, 40, 20};
  static const size_t IIoff[5] = {0, 7864320, 9830400, 10321920, 10444800};

  k_alpha_beta<<<7, 256, 0, stream>>>(oft_b, bn1g, bn1b, bn1m, bn1v,
                                      bn2g, bn2b, bn2m, bn2v, ALPHA, BETA, MEANS, ZPAGE);
  k_wpermT<<<11520, 256, 0, stream>>>(oft_w, WPERMT);
  k_wperm2T<<<2304, 256, 0, stream>>>(conv2_w, WC2T);
  k_bbox<<<(ZC * NBOX + 255) / 256, 256, 0, stream>>>(calib, BBOX);

  k_transpose_all<<<dim3(640, 4), 256, 0, stream>>>(feats[0], feats[1], feats[2],
                                                    feats[3], feats[4], II);
  k_cumw_all<<<186, 256, 0, stream>>>(II);
  k_cumh_all<<<620, 256, 0, stream>>>(II);

  for (int s = 0; s < 5; ++s) {
    k_sample<<<dim3(NBOX / 4, 3), 256, 0, stream>>>(II + IIoff[s], BBOX, VOXT,
                                                    HFs[s], WFs[s],
                                                    (float)(HFs[s] * WFs[s]) * 0.25f);
    k_gemmT<<<dim3(NBLK0, 2, OFT_SPLIT), 256, 0, stream>>>(
        VOXT, WPERMT + (size_t)s * 589824, PART);
    k_redoft<<<NBOX, 256, 0, stream>>>(PART, BETA + s * 256, XBUF, s * 256);
  }
  k_means2<<<(NBOX + 63) / 64, 256, 0, stream>>>(XBUF, MEANS);
  k_att<<<5, 256, 0, stream>>>(MEANS, att_w, att_b, SATT);
  k_wperm1T<<<11520, 256, 0, stream>>>(conv1_w, SATT, WC1T);

  k_gemmS<1><<<dim3(NBLKC, 2, 9), 256, 0, stream>>>(XBUF, WC1T, PART, ZPAGE);
  k_redconv<false><<<NPIX, 256, 0, stream>>>(PART, ALPHA + 5 * 256, BETA + 5 * 256, Y1);

  k_gemmS<2><<<dim3(NBLKC, 2, 9), 256, 0, stream>>>(Y1, WC2T, PART, ZPAGE);
  k_redconv<true><<<NPIX, 256, 0, stream>>>(PART, ALPHA + 6 * 256, BETA + 6 * 256, d_out);
}